// Round 2
// baseline (8359.152 us; speedup 1.0000x reference)
//
#include <hip/hip_runtime.h>
#include <hip/hip_bf16.h>

typedef __hip_bfloat16 bf16;

#define Bn    4
#define NCn   3
#define Hn    112
#define Wn    112
#define Cn    128
#define HEADS 4
#define WSn   7
#define SSn   3
#define HDn   32
#define WNt   1024            // total windows = B * 16 * 16
#define Tt    147             // tokens per window = NC * 49
#define SCALE 0.17677669529663687f

static const size_t NE = (size_t)Bn * NCn * Hn * Wn * Cn; // 19,267,584

__device__ __forceinline__ float bf2f(bf16 v) { return __bfloat162float(v); }
__device__ __forceinline__ bf16  f2bf(float v) { return __float2bfloat16(v); }

// dual-path input load: f==1 -> fp32, f==0 -> bf16
__device__ __forceinline__ float ldi(const void* __restrict__ p, size_t i, int f) {
    return f ? ((const float*)p)[i] : bf2f(((const bf16*)p)[i]);
}

// token (wn, t) -> flat spatial row in (B, NC, H, W) layout (after roll by -SS)
__device__ __forceinline__ int tok_row(int wn, int t) {
    int b = wn >> 8, wrem = wn & 255, wi = wrem >> 4, wj = wrem & 15;
    int n = t / 49, p = t % 49, pi = p / 7, pj = p % 7;
    int i = (wi * 7 + pi + SSn) % Hn;
    int j = (wj * 7 + pj + SSn) % Wn;
    return ((b * NCn + n) * Hn + i) * Wn + j;
}

// Detect input dtype: bf16 pairs have exponent bits (14:7 of each u32) in a
// narrow band for ~N(0,1) data; fp32 has uniform mantissa bits there.
__global__ void k_detect(const unsigned int* __restrict__ xw, int* __restrict__ flag) {
    __shared__ int cnt;
    if (threadIdx.x == 0) cnt = 0;
    __syncthreads();
    int c = 0;
    for (int i = threadIdx.x; i < 8192; i += 256) {
        unsigned e = (xw[i] >> 7) & 0xffu;
        c += (e >= 100u && e <= 140u) ? 1 : 0;
    }
    atomicAdd(&cnt, c);
    __syncthreads();
    if (threadIdx.x == 0) *flag = (cnt < 4096) ? 1 : 0;   // 1 = fp32, 0 = bf16
}

__global__ __launch_bounds__(256) void k_copy(const void* __restrict__ x,
                                              const int* __restrict__ dflag,
                                              bf16* __restrict__ xr) {
    const int f = *dflag;
    size_t idx = (size_t)blockIdx.x * 256 + threadIdx.x;
    xr[idx] = f2bf(ldi(x, idx, f));
}

// Precompute contrast-token projection constants: 4 tables of (3 x 128) fp32
__global__ __launch_bounds__(384) void k_pre(
    const void* __restrict__ ct, const void* __restrict__ ce,
    const void* __restrict__ sa_wq, const void* __restrict__ sa_bq,
    const void* __restrict__ sa_wk, const void* __restrict__ sa_bk,
    const void* __restrict__ ca_wq, const void* __restrict__ ca_bq,
    const void* __restrict__ ca_wk, const void* __restrict__ ca_bk,
    const int* __restrict__ dflag, float* __restrict__ consts) {
    const int f = *dflag;
    int tid = threadIdx.x;          // 384 = 3 * 128
    int n = tid >> 7, c = tid & 127;
    float aq = 0.f, ak = 0.f, aq2 = 0.f, ak2 = 0.f;
    for (int d = 0; d < Cn; ++d) {
        float ctv = ldi(ct, n * Cn + d, f);
        float cev = ldi(ce, n * Cn + d, f);
        aq  += ctv * ldi(sa_wq, d * Cn + c, f);
        ak  += ctv * ldi(sa_wk, d * Cn + c, f);
        aq2 += ctv * ldi(ca_wq, d * Cn + c, f);
        ak2 += cev * ldi(ca_wk, d * Cn + c, f);
    }
    consts[tid]        = aq  + ldi(sa_bq, c, f);
    consts[384 + tid]  = ak  + ldi(sa_bk, c, f);
    consts[768 + tid]  = aq2 + ldi(ca_bq, c, f);
    consts[1152 + tid] = ak2 + ldi(ca_bk, c, f);
}

// LN of one 128-wide bf16 row by one wave; result (bf16) to LDS
__device__ __forceinline__ void ln_row_to_lds(const bf16* __restrict__ row, int lane,
                                              const void* g, const void* bt, int f,
                                              bf16* dst) {
    float a = bf2f(row[lane]), b = bf2f(row[lane + 64]);
    float s = a + b;
    #pragma unroll
    for (int off = 32; off; off >>= 1) s += __shfl_xor(s, off);
    float mean = s * (1.f / 128.f);
    float e0 = a - mean, e1 = b - mean;
    float v = e0 * e0 + e1 * e1;
    #pragma unroll
    for (int off = 32; off; off >>= 1) v += __shfl_xor(v, off);
    float rstd = rsqrtf(v * (1.f / 128.f) + 1e-5f);
    dst[lane]      = f2bf(e0 * rstd * ldi(g, lane, f)      + ldi(bt, lane, f));
    dst[lane + 64] = f2bf(e1 * rstd * ldi(g, lane + 64, f) + ldi(bt, lane + 64, f));
}

// SA stage: LN1 over rolled window tokens, then Q/K/V projections
__global__ __launch_bounds__(256) void k_qkv_sa(
    const bf16* __restrict__ xr, const void* n1g, const void* n1b,
    const void* wq, const void* wk, const void* wv, const void* bv,
    const float* __restrict__ qc, const float* __restrict__ kc,
    const int* __restrict__ dflag,
    bf16* __restrict__ tokQ, bf16* __restrict__ tokK, bf16* __restrict__ tokV) {
    const int f = *dflag;
    __shared__ bf16 ln[Tt][Cn];
    __shared__ int rowIdx[Tt];
    int wn = blockIdx.x, tid = threadIdx.x;
    if (tid < Tt) rowIdx[tid] = tok_row(wn, tid);
    __syncthreads();
    int wave = tid >> 6, lane = tid & 63;
    for (int t = wave; t < Tt; t += 4)
        ln_row_to_lds(xr + (size_t)rowIdx[t] * Cn, lane, n1g, n1b, f, ln[t]);
    __syncthreads();
    int c = tid & 127, half = tid >> 7;
    for (int it = 0; it < 74; ++it) {
        int tt = it * 2 + half;
        if (tt >= Tt) break;
        int n = tt / 49;
        float accq = 0.f, acck = 0.f, accv = 0.f;
        #pragma unroll 4
        for (int d = 0; d < Cn; ++d) {
            float lv = bf2f(ln[tt][d]);
            accq += lv * ldi(wq, d * Cn + c, f);
            acck += lv * ldi(wk, d * Cn + c, f);
            accv += lv * ldi(wv, d * Cn + c, f);
        }
        size_t o = ((size_t)wn * Tt + tt) * Cn + c;
        tokQ[o] = f2bf((accq + qc[n * Cn + c]) * SCALE);
        tokK[o] = f2bf(acck + kc[n * Cn + c]);
        tokV[o] = f2bf(accv + ldi(bv, c, f));
    }
}

// CA stage: Q from LN2(xr)+ct, K/V from rolled x_kv (no LN)
__global__ __launch_bounds__(256) void k_qkv_ca(
    const bf16* __restrict__ xr, const void* __restrict__ xkv,
    const void* n2g, const void* n2b,
    const void* wq, const void* wk, const void* wv, const void* bv,
    const float* __restrict__ qc, const float* __restrict__ kc,
    const int* __restrict__ dflag,
    bf16* __restrict__ tokQ, bf16* __restrict__ tokK, bf16* __restrict__ tokV) {
    const int f = *dflag;
    __shared__ bf16 ln[Tt][Cn];
    __shared__ int rowIdx[Tt];
    int wn = blockIdx.x, tid = threadIdx.x;
    if (tid < Tt) rowIdx[tid] = tok_row(wn, tid);
    __syncthreads();
    int wave = tid >> 6, lane = tid & 63;
    for (int t = wave; t < Tt; t += 4)
        ln_row_to_lds(xr + (size_t)rowIdx[t] * Cn, lane, n2g, n2b, f, ln[t]);
    __syncthreads();
    int c = tid & 127, half = tid >> 7;
    for (int it = 0; it < 74; ++it) {
        int tt = it * 2 + half;
        if (tt >= Tt) break;
        int n = tt / 49;
        float accq = 0.f;
        #pragma unroll 4
        for (int d = 0; d < Cn; ++d)
            accq += bf2f(ln[tt][d]) * ldi(wq, d * Cn + c, f);
        size_t o = ((size_t)wn * Tt + tt) * Cn + c;
        tokQ[o] = f2bf((accq + qc[n * Cn + c]) * SCALE);
    }
    __syncthreads();
    for (int idx = tid; idx < Tt * Cn; idx += 256) {
        int t = idx >> 7, d = idx & 127;
        ln[t][d] = f2bf(ldi(xkv, (size_t)rowIdx[t] * Cn + d, f));
    }
    __syncthreads();
    for (int it = 0; it < 74; ++it) {
        int tt = it * 2 + half;
        if (tt >= Tt) break;
        int n = tt / 49;
        float acck = 0.f, accv = 0.f;
        #pragma unroll 4
        for (int d = 0; d < Cn; ++d) {
            float lv = bf2f(ln[tt][d]);
            acck += lv * ldi(wk, d * Cn + c, f);
            accv += lv * ldi(wv, d * Cn + c, f);
        }
        size_t o = ((size_t)wn * Tt + tt) * Cn + c;
        tokK[o] = f2bf(acck + kc[n * Cn + c]);
        tokV[o] = f2bf(accv + ldi(bv, c, f));
    }
}

// Attention core: one block per (window, head). O aliases Q (block reads its own
// slice into LDS before writing the same slice — alias-safe).
__global__ __launch_bounds__(256) void k_attn(
    const bf16* __restrict__ Q, const bf16* __restrict__ K, const bf16* __restrict__ V,
    bf16* __restrict__ O, const void* __restrict__ rpb, const int* __restrict__ dflag) {
    const int f = *dflag;
    __shared__ float Qs[Tt * HDn];
    __shared__ float Ks[Tt * HDn];
    __shared__ float Vs[Tt * HDn];
    __shared__ float rpbl[169];
    __shared__ int pis[Tt], pjs[Tt], regs[Tt];
    int wn = blockIdx.x, h = blockIdx.y, tid = threadIdx.x;
    int wrem = wn & 255, wi = wrem >> 4, wj = wrem & 15;
    size_t base = (size_t)wn * Tt * Cn + h * HDn;
    for (int idx = tid; idx < Tt * HDn; idx += 256) {
        int t = idx >> 5, d = idx & 31;
        size_t g = base + (size_t)t * Cn + d;
        Qs[idx] = bf2f(Q[g]);
        Ks[idx] = bf2f(K[g]);
        Vs[idx] = bf2f(V[g]);
    }
    if (tid < 169) rpbl[tid] = ldi(rpb, tid * HEADS + h, f);
    if (tid < Tt) {
        int p = tid % 49, pi = p / 7, pj = p % 7;
        pis[tid] = pi; pjs[tid] = pj;
        int ir = wi * 7 + pi, jr = wj * 7 + pj;
        int ri = ir < 105 ? 0 : (ir < 109 ? 1 : 2);
        int rj = jr < 105 ? 0 : (jr < 109 ? 1 : 2);
        regs[tid] = ri * 3 + rj;
    }
    __syncthreads();
    if (tid >= Tt) return;
    float q[HDn];
    #pragma unroll
    for (int d = 0; d < HDn; ++d) q[d] = Qs[tid * HDn + d];
    int piq = pis[tid], pjq = pjs[tid], rq = regs[tid];
    float m = -1e30f, l = 0.f;
    for (int j = 0; j < Tt; ++j) {
        float s = 0.f;
        const float4* kk = (const float4*)&Ks[j * HDn];
        #pragma unroll
        for (int d4 = 0; d4 < 8; ++d4) {
            float4 kv = kk[d4];
            s += q[d4*4+0]*kv.x + q[d4*4+1]*kv.y + q[d4*4+2]*kv.z + q[d4*4+3]*kv.w;
        }
        s += rpbl[(piq - pis[j] + 6) * 13 + (pjq - pjs[j] + 6)];
        if (rq != regs[j]) s -= 100.f;
        if (s > m) { l = l * __expf(m - s) + 1.f; m = s; }
        else       { l += __expf(s - m); }
    }
    float o[HDn];
    #pragma unroll
    for (int d = 0; d < HDn; ++d) o[d] = 0.f;
    for (int j = 0; j < Tt; ++j) {
        float s = 0.f;
        const float4* kk = (const float4*)&Ks[j * HDn];
        #pragma unroll
        for (int d4 = 0; d4 < 8; ++d4) {
            float4 kv = kk[d4];
            s += q[d4*4+0]*kv.x + q[d4*4+1]*kv.y + q[d4*4+2]*kv.z + q[d4*4+3]*kv.w;
        }
        s += rpbl[(piq - pis[j] + 6) * 13 + (pjq - pjs[j] + 6)];
        if (rq != regs[j]) s -= 100.f;
        float p = __expf(s - m);
        const float4* vv = (const float4*)&Vs[j * HDn];
        #pragma unroll
        for (int d4 = 0; d4 < 8; ++d4) {
            float4 v4 = vv[d4];
            o[d4*4+0] += p * v4.x; o[d4*4+1] += p * v4.y;
            o[d4*4+2] += p * v4.z; o[d4*4+3] += p * v4.w;
        }
    }
    float inv = 1.f / l;
    #pragma unroll
    for (int d = 0; d < HDn; ++d)
        O[base + (size_t)tid * Cn + d] = f2bf(o[d] * inv);
}

// Output projection of attention + residual add into xr (bf16 RMW, block-disjoint rows)
__global__ __launch_bounds__(256) void k_proj_scatter(
    const bf16* __restrict__ tokO, const void* wp, const void* bp,
    const int* __restrict__ dflag, bf16* __restrict__ xr) {
    const int f = *dflag;
    __shared__ bf16 Ol[Tt][Cn];
    int wn = blockIdx.x, tid = threadIdx.x;
    for (int idx = tid; idx < Tt * Cn; idx += 256) {
        int t = idx >> 7, d = idx & 127;
        Ol[t][d] = tokO[((size_t)wn * Tt + t) * Cn + d];
    }
    __syncthreads();
    int c = tid & 127, half = tid >> 7;
    for (int it = 0; it < 74; ++it) {
        int tt = it * 2 + half;
        if (tt >= Tt) break;
        float acc = 0.f;
        #pragma unroll 4
        for (int d = 0; d < Cn; ++d)
            acc += bf2f(Ol[tt][d]) * ldi(wp, d * Cn + c, f);
        size_t o = (size_t)tok_row(wn, tt) * Cn + c;
        xr[o] = f2bf(bf2f(xr[o]) + acc + ldi(bp, c, f));
    }
}

// LN3 for every token row -> ln3 buffer (bf16)
__global__ __launch_bounds__(256) void k_ln3(
    const bf16* __restrict__ xr, const void* g, const void* b,
    const int* __restrict__ dflag, bf16* __restrict__ out) {
    const int f = *dflag;
    int row = blockIdx.x * 4 + (threadIdx.x >> 6);
    int lane = threadIdx.x & 63;
    const bf16* r = xr + (size_t)row * Cn;
    float a = bf2f(r[lane]), bb = bf2f(r[lane + 64]);
    float s = a + bb;
    #pragma unroll
    for (int off = 32; off; off >>= 1) s += __shfl_xor(s, off);
    float mean = s * (1.f / 128.f);
    float e0 = a - mean, e1 = bb - mean;
    float v = e0 * e0 + e1 * e1;
    #pragma unroll
    for (int off = 32; off; off >>= 1) v += __shfl_xor(v, off);
    float rstd = rsqrtf(v * (1.f / 128.f) + 1e-5f);
    out[(size_t)row * Cn + lane]      = f2bf(e0 * rstd * ldi(g, lane, f)      + ldi(b, lane, f));
    out[(size_t)row * Cn + lane + 64] = f2bf(e1 * rstd * ldi(g, lane + 64, f) + ldi(b, lane + 64, f));
}

// MLP: out = xr + (gelu(ln3 @ w1 + b1) @ w2 + b2), 2 tokens per block; dual-dtype store
__global__ __launch_bounds__(256) void k_mlp(
    const bf16* __restrict__ xr, const bf16* __restrict__ ln3,
    const void* w1, const void* b1, const void* w2, const void* b2,
    const int* __restrict__ dflag, void* __restrict__ outp) {
    const int f = *dflag;
    __shared__ float h1[2][512];
    __shared__ bf16 lr[2][Cn];
    int t0 = blockIdx.x * 2, tid = threadIdx.x;
    {
        int t = tid >> 7, d = tid & 127;
        lr[t][d] = ln3[(size_t)(t0 + t) * Cn + d];
    }
    __syncthreads();
    #pragma unroll
    for (int rep = 0; rep < 4; ++rep) {
        int u = rep * 256 + tid;
        int t = u >> 9, hh = u & 511;
        float acc = 0.f;
        #pragma unroll 4
        for (int d = 0; d < Cn; ++d)
            acc += bf2f(lr[t][d]) * ldi(w1, d * 512 + hh, f);
        acc += ldi(b1, hh, f);
        h1[t][hh] = 0.5f * acc * (1.f + erff(acc * 0.70710678118654752f));
    }
    __syncthreads();
    {
        int t = tid >> 7, c = tid & 127;
        float acc = 0.f;
        #pragma unroll 4
        for (int hh = 0; hh < 512; ++hh)
            acc += h1[t][hh] * ldi(w2, hh * Cn + c, f);
        size_t row = (size_t)(t0 + t) * Cn + c;
        float res = bf2f(xr[row]) + acc + ldi(b2, c, f);
        if (f) ((float*)outp)[row] = res;
        else   ((bf16*)outp)[row]  = f2bf(res);
    }
}

extern "C" void kernel_launch(void* const* d_in, const int* in_sizes, int n_in,
                              void* d_out, int out_size, void* d_ws, size_t ws_size,
                              hipStream_t stream) {
    const void* x      = d_in[0];
    const void* xkv    = d_in[1];
    const void* ct     = d_in[2];
    const void* ce     = d_in[3];
    const void* n1g    = d_in[4];
    const void* n1b    = d_in[5];
    const void* n2g    = d_in[6];
    const void* n2b    = d_in[7];
    const void* n3g    = d_in[8];
    const void* n3b    = d_in[9];
    const void* sa_wq  = d_in[10];
    const void* sa_bq  = d_in[11];
    const void* sa_wk  = d_in[12];
    const void* sa_bk  = d_in[13];
    const void* sa_wv  = d_in[14];
    const void* sa_bv  = d_in[15];
    const void* sa_wp  = d_in[16];
    const void* sa_bp  = d_in[17];
    const void* sa_rpb = d_in[18];
    const void* ca_wq  = d_in[19];
    const void* ca_bq  = d_in[20];
    const void* ca_wk  = d_in[21];
    const void* ca_bk  = d_in[22];
    const void* ca_wv  = d_in[23];
    const void* ca_bv  = d_in[24];
    const void* ca_wp  = d_in[25];
    const void* ca_bp  = d_in[26];
    const void* ca_rpb = d_in[27];
    const void* m_w1   = d_in[28];
    const void* m_b1   = d_in[29];
    const void* m_w2   = d_in[30];
    const void* m_b2   = d_in[31];

    // ws layout (total ~115.6 MB): consts(6KB) | flag | xr | tokK | tokV
    char* base = (char*)d_ws;
    float* consts = (float*)base;                 // 1536 f32
    int*   dflag  = (int*)(base + 6144);
    bf16*  xr     = (bf16*)(base + 8192);         // NE bf16 residual
    bf16*  tokK   = xr + NE;
    bf16*  tokV   = tokK + NE;
    bf16*  tokQ   = (bf16*)d_out;                 // Q and O alias in d_out

    int nblk = (int)(NE / 256);                   // 75,264

    k_detect<<<1, 256, 0, stream>>>((const unsigned int*)x, dflag);
    k_copy<<<nblk, 256, 0, stream>>>(x, dflag, xr);
    k_pre<<<1, 384, 0, stream>>>(ct, ce, sa_wq, sa_bq, sa_wk, sa_bk,
                                 ca_wq, ca_bq, ca_wk, ca_bk, dflag, consts);
    // ---- self-attention stage ----
    k_qkv_sa<<<WNt, 256, 0, stream>>>(xr, n1g, n1b, sa_wq, sa_wk, sa_wv, sa_bv,
                                      consts, consts + 384, dflag, tokQ, tokK, tokV);
    k_attn<<<dim3(WNt, HEADS), 256, 0, stream>>>(tokQ, tokK, tokV, tokQ, sa_rpb, dflag);
    k_proj_scatter<<<WNt, 256, 0, stream>>>(tokQ, sa_wp, sa_bp, dflag, xr);
    // ---- cross-attention stage ----
    k_qkv_ca<<<WNt, 256, 0, stream>>>(xr, xkv, n2g, n2b, ca_wq, ca_wk, ca_wv, ca_bv,
                                      consts + 768, consts + 1152, dflag, tokQ, tokK, tokV);
    k_attn<<<dim3(WNt, HEADS), 256, 0, stream>>>(tokQ, tokK, tokV, tokQ, ca_rpb, dflag);
    k_proj_scatter<<<WNt, 256, 0, stream>>>(tokQ, ca_wp, ca_bp, dflag, xr);
    // ---- MLP stage ----
    k_ln3<<<(int)(NE / Cn / 4), 256, 0, stream>>>(xr, n3g, n3b, dflag, tokK);
    k_mlp<<<(int)(NE / Cn / 2), 256, 0, stream>>>(xr, tokK, m_w1, m_b1, m_w2, m_b2,
                                                  dflag, d_out);
}

// Round 3
// 2758.076 us; speedup vs baseline: 3.0308x; 3.0308x over previous
//
#include <hip/hip_runtime.h>
#include <hip/hip_bf16.h>

typedef __hip_bfloat16 bf16;

#define Bn    4
#define NCn   3
#define Hn    112
#define Wn    112
#define Cn    128
#define HEADS 4
#define WSn   7
#define SSn   3
#define HDn   32
#define WNt   1024            // total windows = B * 16 * 16
#define Tt    147             // tokens per window = NC * 49
#define SCALE 0.17677669529663687f

static const size_t NE = (size_t)Bn * NCn * Hn * Wn * Cn; // 19,267,584

typedef float f32x4 __attribute__((ext_vector_type(4)));
typedef short s16x8 __attribute__((ext_vector_type(8)));
#define MFMA(a,b,c) __builtin_amdgcn_mfma_f32_16x16x32_bf16((a),(b),(c),0,0,0)

// P (f32 param block) offsets
#define P_QCSA 0
#define P_KCSA 384
#define P_QCCA 768
#define P_KCCA 1152
#define P_VCSA 1536
#define P_BPSA 1664
#define P_VCCA 1792
#define P_BPCA 1920
#define P_B1   2048
#define P_B2   2560
#define P_G1   2688
#define P_N1B  2816
#define P_G2   2944
#define P_N2B  3072
#define P_G3   3200
#define P_N3B  3328
#define P_RPBSA 3456
#define P_RPBCA 4132

// wT (bf16 transposed-weight block) offsets, elements
#define W_SAQ 0
#define W_SAK 16384
#define W_SAV 32768
#define W_SAP 49152
#define W_CAQ 65536
#define W_CAK 81920
#define W_CAV 98304
#define W_CAP 114688
#define W_W1T 131072
#define W_W2T 196608

struct Ptrs { const void* p[32]; };

__device__ __forceinline__ float bf2f(bf16 v) { return __bfloat162float(v); }
__device__ __forceinline__ bf16  f2bf(float v) { return __float2bfloat16(v); }
__device__ __forceinline__ short f2bs(float v) { bf16 t = __float2bfloat16(v); return *reinterpret_cast<short*>(&t); }

// dual-path input load: f==1 -> fp32, f==0 -> bf16
__device__ __forceinline__ float ldi(const void* __restrict__ p, size_t i, int f) {
    return f ? ((const float*)p)[i] : bf2f(((const bf16*)p)[i]);
}

// token (wn, t) -> flat spatial row in (B, NC, H, W) layout (after roll by -SS)
__device__ __forceinline__ int tok_row(int wn, int t) {
    int b = wn >> 8, wrem = wn & 255, wi = wrem >> 4, wj = wrem & 15;
    int n = t / 49, p = t % 49, pi = p / 7, pj = p % 7;
    int i = (wi * 7 + pi + SSn) % Hn;
    int j = (wj * 7 + pj + SSn) % Wn;
    return ((b * NCn + n) * Hn + i) * Wn + j;
}

// Detect input dtype (bf16 exponent-band heuristic)
__global__ void k_detect(const unsigned int* __restrict__ xw, int* __restrict__ flag) {
    __shared__ int cnt;
    if (threadIdx.x == 0) cnt = 0;
    __syncthreads();
    int c = 0;
    for (int i = threadIdx.x; i < 8192; i += 256) {
        unsigned e = (xw[i] >> 7) & 0xffu;
        c += (e >= 100u && e <= 140u) ? 1 : 0;
    }
    atomicAdd(&cnt, c);
    __syncthreads();
    if (threadIdx.x == 0) *flag = (cnt < 4096) ? 1 : 0;   // 1 = fp32, 0 = bf16
}

__global__ __launch_bounds__(256) void k_copy(const void* __restrict__ x,
                                              const int* __restrict__ dflag,
                                              bf16* __restrict__ xr) {
    const int f = *dflag;
    size_t i8 = ((size_t)blockIdx.x * 256 + threadIdx.x) * 8;
    s16x8 v;
    if (f) {
        const float* s = (const float*)x + i8;
        #pragma unroll
        for (int j = 0; j < 8; ++j) v[j] = f2bs(s[j]);
    } else {
        v = *(const s16x8*)((const bf16*)x + i8);
    }
    *(s16x8*)(xr + i8) = v;
}

// All scalar parameter prep: contrast-token projections, biases, LN params, rpb tables
__global__ __launch_bounds__(512) void k_params(Ptrs in, const int* __restrict__ dflag,
                                                float* __restrict__ P) {
    const int f = *dflag;
    int tid = threadIdx.x;
    if (tid < 384) {
        int n = tid >> 7, c = tid & 127;
        float aq = 0.f, ak = 0.f, aq2 = 0.f, ak2 = 0.f;
        for (int d = 0; d < Cn; ++d) {
            float ctv = ldi(in.p[2], n * Cn + d, f);
            float cev = ldi(in.p[3], n * Cn + d, f);
            aq  += ctv * ldi(in.p[10], d * Cn + c, f);
            ak  += ctv * ldi(in.p[12], d * Cn + c, f);
            aq2 += ctv * ldi(in.p[19], d * Cn + c, f);
            ak2 += cev * ldi(in.p[21], d * Cn + c, f);
        }
        P[P_QCSA + tid] = aq  + ldi(in.p[11], tid & 127, f);
        P[P_KCSA + tid] = ak  + ldi(in.p[13], tid & 127, f);
        P[P_QCCA + tid] = aq2 + ldi(in.p[20], tid & 127, f);
        P[P_KCCA + tid] = ak2 + ldi(in.p[22], tid & 127, f);
    }
    if (tid < 128) {
        P[P_VCSA + tid] = ldi(in.p[15], tid, f);
        P[P_BPSA + tid] = ldi(in.p[17], tid, f);
        P[P_VCCA + tid] = ldi(in.p[24], tid, f);
        P[P_BPCA + tid] = ldi(in.p[26], tid, f);
        P[P_B2   + tid] = ldi(in.p[31], tid, f);
        P[P_G1   + tid] = ldi(in.p[4],  tid, f);
        P[P_N1B  + tid] = ldi(in.p[5],  tid, f);
        P[P_G2   + tid] = ldi(in.p[6],  tid, f);
        P[P_N2B  + tid] = ldi(in.p[7],  tid, f);
        P[P_G3   + tid] = ldi(in.p[8],  tid, f);
        P[P_N3B  + tid] = ldi(in.p[9],  tid, f);
    }
    P[P_B1 + tid] = ldi(in.p[29], tid, f);
    for (int i = tid; i < 676; i += 512) {
        P[P_RPBSA + (i & 3) * 169 + (i >> 2)] = ldi(in.p[18], i, f);
        P[P_RPBCA + (i & 3) * 169 + (i >> 2)] = ldi(in.p[27], i, f);
    }
}

// Transpose 8 square 128x128 weights to n-major bf16
__global__ __launch_bounds__(128) void k_tsq(Ptrs in, const int* __restrict__ dflag,
                                             bf16* __restrict__ wT) {
    const int f = *dflag;
    const int map[8] = {10, 12, 14, 16, 19, 21, 23, 25};
    int mat = blockIdx.y, n = blockIdx.x, k = threadIdx.x;
    wT[mat * 16384 + n * 128 + k] = f2bf(ldi(in.p[map[mat]], k * 128 + n, f));
}

// Transpose MLP weights: w1 (128x512) -> w1t[512][128]; w2 (512x128) -> w2t[128][512]
__global__ __launch_bounds__(512) void k_tmlp(Ptrs in, const int* __restrict__ dflag,
                                              bf16* __restrict__ wT) {
    const int f = *dflag;
    int bid = blockIdx.x, tid = threadIdx.x;
    if (bid < 512) {
        if (tid < 128) wT[W_W1T + bid * 128 + tid] = f2bf(ldi(in.p[28], tid * 512 + bid, f));
    } else {
        int n = bid - 512;
        wT[W_W2T + n * 512 + tid] = f2bf(ldi(in.p[30], tid * 128 + n, f));
    }
}

// LN of one 128-wide bf16 row by one wave; bf16 result into XOR-swizzled LDS row t (stride 256B)
__device__ __forceinline__ void ln_row_swz(const bf16* __restrict__ row, int lane,
                                           const float* __restrict__ g, const float* __restrict__ b,
                                           char* __restrict__ lds, int t) {
    float a = bf2f(row[lane]), c = bf2f(row[lane + 64]);
    float s = a + c;
    #pragma unroll
    for (int off = 32; off; off >>= 1) s += __shfl_xor(s, off);
    float mean = s * (1.f / 128.f);
    float e0 = a - mean, e1 = c - mean;
    float v = e0 * e0 + e1 * e1;
    #pragma unroll
    for (int off = 32; off; off >>= 1) v += __shfl_xor(v, off);
    float rstd = rsqrtf(v * (1.f / 128.f) + 1e-5f);
    int sw = (t & 7) << 4;
    *(bf16*)(lds + t * 256 + ((lane * 2) ^ sw))        = f2bf(e0 * rstd * g[lane] + b[lane]);
    *(bf16*)(lds + t * 256 + (((lane + 64) * 2) ^ sw)) = f2bf(e1 * rstd * g[lane + 64] + b[lane + 64]);
}

// SA: gather+LN1 -> LDS, then Q/K/V = LDS @ wT via MFMA
__global__ __launch_bounds__(256) void k_qkv_sa(
    const bf16* __restrict__ xr, const float* __restrict__ P, const bf16* __restrict__ wT,
    bf16* __restrict__ tokQ, bf16* __restrict__ tokK, bf16* __restrict__ tokV) {
    __shared__ char ldsA[160 * 256];
    __shared__ int rowIdx[Tt];
    int wn = blockIdx.x, tid = threadIdx.x;
    if (tid < Tt) rowIdx[tid] = tok_row(wn, tid);
    for (int i = tid; i < 13 * 128; i += 256) ((short*)(ldsA + 147 * 256))[i] = 0;
    __syncthreads();
    int wv = tid >> 6, lane = tid & 63;
    for (int t = wv; t < Tt; t += 4)
        ln_row_swz(xr + (size_t)rowIdx[t] * Cn, lane, P + P_G1, P + P_N1B, ldsA, t);
    __syncthreads();
    int l15 = lane & 15, lg = lane >> 4, sw = (l15 & 7) << 4;
    #pragma unroll 1
    for (int mat = 0; mat < 3; ++mat) {
        const bf16* W = wT + mat * 16384;
        bf16* dst = mat == 0 ? tokQ : (mat == 1 ? tokK : tokV);
        #pragma unroll 1
        for (int ni = 0; ni < 2; ++ni) {
            int nt = wv * 2 + ni;
            f32x4 acc[10] = {};
            for (int ks = 0; ks < 4; ++ks) {
                s16x8 bfrag = *(const s16x8*)(W + ((nt * 16 + l15) << 7) + ks * 32 + lg * 8);
                #pragma unroll
                for (int mt = 0; mt < 10; ++mt) {
                    int row = mt * 16 + l15;
                    s16x8 af = *(const s16x8*)(ldsA + row * 256 + ((ks * 64 + lg * 16) ^ sw));
                    acc[mt] = MFMA(af, bfrag, acc[mt]);
                }
            }
            int col = nt * 16 + l15;
            #pragma unroll
            for (int mt = 0; mt < 10; ++mt) {
                #pragma unroll
                for (int r = 0; r < 4; ++r) {
                    int row = mt * 16 + lg * 4 + r;
                    if (row < Tt) {
                        int n = row / 49;
                        float v = acc[mt][r];
                        float o = (mat == 0) ? (v + P[P_QCSA + n * 128 + col]) * SCALE
                                : (mat == 1) ? v + P[P_KCSA + n * 128 + col]
                                             : v + P[P_VCSA + col];
                        dst[((size_t)wn * Tt + row) * Cn + col] = f2bf(o);
                    }
                }
            }
        }
    }
}

// CA: Q from LN2(xr); K/V from gathered x_kv (dual-dtype)
__global__ __launch_bounds__(256) void k_qkv_ca(
    const bf16* __restrict__ xr, const void* __restrict__ xkv,
    const float* __restrict__ P, const bf16* __restrict__ wT,
    const int* __restrict__ dflag,
    bf16* __restrict__ tokQ, bf16* __restrict__ tokK, bf16* __restrict__ tokV) {
    const int f = *dflag;
    __shared__ char ldsA[160 * 256];
    __shared__ int rowIdx[Tt];
    int wn = blockIdx.x, tid = threadIdx.x;
    if (tid < Tt) rowIdx[tid] = tok_row(wn, tid);
    for (int i = tid; i < 13 * 128; i += 256) ((short*)(ldsA + 147 * 256))[i] = 0;
    __syncthreads();
    int wv = tid >> 6, lane = tid & 63;
    for (int t = wv; t < Tt; t += 4)
        ln_row_swz(xr + (size_t)rowIdx[t] * Cn, lane, P + P_G2, P + P_N2B, ldsA, t);
    __syncthreads();
    int l15 = lane & 15, lg = lane >> 4, sw = (l15 & 7) << 4;
    // Q projection
    {
        const bf16* W = wT + W_CAQ;
        #pragma unroll 1
        for (int ni = 0; ni < 2; ++ni) {
            int nt = wv * 2 + ni;
            f32x4 acc[10] = {};
            for (int ks = 0; ks < 4; ++ks) {
                s16x8 bfrag = *(const s16x8*)(W + ((nt * 16 + l15) << 7) + ks * 32 + lg * 8);
                #pragma unroll
                for (int mt = 0; mt < 10; ++mt) {
                    int row = mt * 16 + l15;
                    s16x8 af = *(const s16x8*)(ldsA + row * 256 + ((ks * 64 + lg * 16) ^ sw));
                    acc[mt] = MFMA(af, bfrag, acc[mt]);
                }
            }
            int col = nt * 16 + l15;
            #pragma unroll
            for (int mt = 0; mt < 10; ++mt) {
                #pragma unroll
                for (int r = 0; r < 4; ++r) {
                    int row = mt * 16 + lg * 4 + r;
                    if (row < Tt) {
                        int n = row / 49;
                        tokQ[((size_t)wn * Tt + row) * Cn + col] =
                            f2bf((acc[mt][r] + P[P_QCCA + n * 128 + col]) * SCALE);
                    }
                }
            }
        }
    }
    __syncthreads();
    // gather x_kv into LDS (swizzled)
    for (int idx = tid; idx < Tt * 16; idx += 256) {
        int t = idx >> 4, c8 = idx & 15;
        s16x8 v;
        if (f) {
            const float* s = (const float*)xkv + (size_t)rowIdx[t] * Cn + c8 * 8;
            #pragma unroll
            for (int j = 0; j < 8; ++j) v[j] = f2bs(s[j]);
        } else {
            v = *(const s16x8*)((const bf16*)xkv + (size_t)rowIdx[t] * Cn + c8 * 8);
        }
        *(s16x8*)(ldsA + t * 256 + ((c8 * 16) ^ ((t & 7) << 4))) = v;
    }
    __syncthreads();
    #pragma unroll 1
    for (int mat = 0; mat < 2; ++mat) {
        const bf16* W = wT + (mat == 0 ? W_CAK : W_CAV);
        bf16* dst = mat == 0 ? tokK : tokV;
        #pragma unroll 1
        for (int ni = 0; ni < 2; ++ni) {
            int nt = wv * 2 + ni;
            f32x4 acc[10] = {};
            for (int ks = 0; ks < 4; ++ks) {
                s16x8 bfrag = *(const s16x8*)(W + ((nt * 16 + l15) << 7) + ks * 32 + lg * 8);
                #pragma unroll
                for (int mt = 0; mt < 10; ++mt) {
                    int row = mt * 16 + l15;
                    s16x8 af = *(const s16x8*)(ldsA + row * 256 + ((ks * 64 + lg * 16) ^ sw));
                    acc[mt] = MFMA(af, bfrag, acc[mt]);
                }
            }
            int col = nt * 16 + l15;
            #pragma unroll
            for (int mt = 0; mt < 10; ++mt) {
                #pragma unroll
                for (int r = 0; r < 4; ++r) {
                    int row = mt * 16 + lg * 4 + r;
                    if (row < Tt) {
                        int n = row / 49;
                        float o = (mat == 0) ? acc[mt][r] + P[P_KCCA + n * 128 + col]
                                             : acc[mt][r] + P[P_VCCA + col];
                        dst[((size_t)wn * Tt + row) * Cn + col] = f2bf(o);
                    }
                }
            }
        }
    }
}

// Attention core (unchanged math): one block per (window, head), O aliases Q
__global__ __launch_bounds__(256) void k_attn(
    const bf16* __restrict__ Q, const bf16* __restrict__ K, const bf16* __restrict__ V,
    bf16* __restrict__ O, const float* __restrict__ rpbf) {
    __shared__ float Qs[Tt * HDn];
    __shared__ float Ks[Tt * HDn];
    __shared__ float Vs[Tt * HDn];
    __shared__ float rpbl[169];
    __shared__ int pis[Tt], pjs[Tt], regs[Tt];
    int wn = blockIdx.x, h = blockIdx.y, tid = threadIdx.x;
    int wrem = wn & 255, wi = wrem >> 4, wj = wrem & 15;
    size_t base = (size_t)wn * Tt * Cn + h * HDn;
    for (int idx = tid; idx < Tt * HDn; idx += 256) {
        int t = idx >> 5, d = idx & 31;
        size_t g = base + (size_t)t * Cn + d;
        Qs[idx] = bf2f(Q[g]);
        Ks[idx] = bf2f(K[g]);
        Vs[idx] = bf2f(V[g]);
    }
    if (tid < 169) rpbl[tid] = rpbf[h * 169 + tid];
    if (tid < Tt) {
        int p = tid % 49, pi = p / 7, pj = p % 7;
        pis[tid] = pi; pjs[tid] = pj;
        int ir = wi * 7 + pi, jr = wj * 7 + pj;
        int ri = ir < 105 ? 0 : (ir < 109 ? 1 : 2);
        int rj = jr < 105 ? 0 : (jr < 109 ? 1 : 2);
        regs[tid] = ri * 3 + rj;
    }
    __syncthreads();
    if (tid >= Tt) return;
    float q[HDn];
    #pragma unroll
    for (int d = 0; d < HDn; ++d) q[d] = Qs[tid * HDn + d];
    int piq = pis[tid], pjq = pjs[tid], rq = regs[tid];
    float m = -1e30f, l = 0.f;
    for (int j = 0; j < Tt; ++j) {
        float s = 0.f;
        const float4* kk = (const float4*)&Ks[j * HDn];
        #pragma unroll
        for (int d4 = 0; d4 < 8; ++d4) {
            float4 kv = kk[d4];
            s += q[d4*4+0]*kv.x + q[d4*4+1]*kv.y + q[d4*4+2]*kv.z + q[d4*4+3]*kv.w;
        }
        s += rpbl[(piq - pis[j] + 6) * 13 + (pjq - pjs[j] + 6)];
        if (rq != regs[j]) s -= 100.f;
        if (s > m) { l = l * __expf(m - s) + 1.f; m = s; }
        else       { l += __expf(s - m); }
    }
    float o[HDn];
    #pragma unroll
    for (int d = 0; d < HDn; ++d) o[d] = 0.f;
    for (int j = 0; j < Tt; ++j) {
        float s = 0.f;
        const float4* kk = (const float4*)&Ks[j * HDn];
        #pragma unroll
        for (int d4 = 0; d4 < 8; ++d4) {
            float4 kv = kk[d4];
            s += q[d4*4+0]*kv.x + q[d4*4+1]*kv.y + q[d4*4+2]*kv.z + q[d4*4+3]*kv.w;
        }
        s += rpbl[(piq - pis[j] + 6) * 13 + (pjq - pjs[j] + 6)];
        if (rq != regs[j]) s -= 100.f;
        float p = __expf(s - m);
        const float4* vv = (const float4*)&Vs[j * HDn];
        #pragma unroll
        for (int d4 = 0; d4 < 8; ++d4) {
            float4 v4 = vv[d4];
            o[d4*4+0] += p * v4.x; o[d4*4+1] += p * v4.y;
            o[d4*4+2] += p * v4.z; o[d4*4+3] += p * v4.w;
        }
    }
    float inv = 1.f / l;
    #pragma unroll
    for (int d = 0; d < HDn; ++d)
        O[base + (size_t)tid * Cn + d] = f2bf(o[d] * inv);
}

// Output projection of attention (MFMA) + residual scatter-add into xr
__global__ __launch_bounds__(256) void k_proj(
    const bf16* __restrict__ tokO, const float* __restrict__ P, const bf16* __restrict__ W,
    int bpOff, bf16* __restrict__ xr) {
    __shared__ char ldsA[160 * 256];
    __shared__ int rowIdx[Tt];
    int wn = blockIdx.x, tid = threadIdx.x;
    if (tid < Tt) rowIdx[tid] = tok_row(wn, tid);
    for (int i = tid; i < 13 * 128; i += 256) ((short*)(ldsA + 147 * 256))[i] = 0;
    __syncthreads();
    for (int idx = tid; idx < Tt * 16; idx += 256) {
        int t = idx >> 4, c8 = idx & 15;
        s16x8 v = *(const s16x8*)(tokO + ((size_t)wn * Tt + t) * Cn + c8 * 8);
        *(s16x8*)(ldsA + t * 256 + ((c8 * 16) ^ ((t & 7) << 4))) = v;
    }
    __syncthreads();
    int wv = tid >> 6, lane = tid & 63;
    int l15 = lane & 15, lg = lane >> 4, sw = (l15 & 7) << 4;
    #pragma unroll 1
    for (int ni = 0; ni < 2; ++ni) {
        int nt = wv * 2 + ni;
        f32x4 acc[10] = {};
        for (int ks = 0; ks < 4; ++ks) {
            s16x8 bfrag = *(const s16x8*)(W + ((nt * 16 + l15) << 7) + ks * 32 + lg * 8);
            #pragma unroll
            for (int mt = 0; mt < 10; ++mt) {
                int row = mt * 16 + l15;
                s16x8 af = *(const s16x8*)(ldsA + row * 256 + ((ks * 64 + lg * 16) ^ sw));
                acc[mt] = MFMA(af, bfrag, acc[mt]);
            }
        }
        int col = nt * 16 + l15;
        #pragma unroll
        for (int mt = 0; mt < 10; ++mt) {
            #pragma unroll
            for (int r = 0; r < 4; ++r) {
                int row = mt * 16 + lg * 4 + r;
                if (row < Tt) {
                    size_t o = (size_t)rowIdx[row] * Cn + col;
                    xr[o] = f2bf(bf2f(xr[o]) + acc[mt][r] + P[bpOff + col]);
                }
            }
        }
    }
}

// Fused LN3 + MLP (two MFMA GEMMs, h1 in LDS) + residual; dual-dtype output store
__global__ __launch_bounds__(256) void k_mlp(
    const bf16* __restrict__ xr, const float* __restrict__ P, const bf16* __restrict__ wT,
    const int* __restrict__ dflag, void* __restrict__ outp) {
    __shared__ char ldsA[64 * 256];    // 16 KB  LN3 tile
    __shared__ char ldsH[64 * 1024];   // 64 KB  h1 tile
    int tid = threadIdx.x;
    size_t t0 = (size_t)blockIdx.x * 64;
    int wv = tid >> 6, lane = tid & 63;
    for (int t = wv; t < 64; t += 4)
        ln_row_swz(xr + (t0 + t) * Cn, lane, P + P_G3, P + P_N3B, ldsA, t);
    __syncthreads();
    int l15 = lane & 15, lg = lane >> 4, sw = (l15 & 7) << 4;
    const bf16* W1 = wT + W_W1T;
    #pragma unroll 1
    for (int ni = 0; ni < 8; ++ni) {
        int nt = wv * 8 + ni;
        f32x4 acc[4] = {};
        for (int ks = 0; ks < 4; ++ks) {
            s16x8 bfrag = *(const s16x8*)(W1 + ((nt * 16 + l15) << 7) + ks * 32 + lg * 8);
            #pragma unroll
            for (int mt = 0; mt < 4; ++mt) {
                int row = mt * 16 + l15;
                s16x8 af = *(const s16x8*)(ldsA + row * 256 + ((ks * 64 + lg * 16) ^ sw));
                acc[mt] = MFMA(af, bfrag, acc[mt]);
            }
        }
        int col = nt * 16 + l15;
        #pragma unroll
        for (int mt = 0; mt < 4; ++mt) {
            #pragma unroll
            for (int r = 0; r < 4; ++r) {
                int row = mt * 16 + lg * 4 + r;
                float v = acc[mt][r] + P[P_B1 + col];
                float g = 0.5f * v * (1.f + erff(v * 0.70710678118654752f));
                *(bf16*)(ldsH + row * 1024 + ((col * 2) ^ ((row & 7) << 4))) = f2bf(g);
            }
        }
    }
    __syncthreads();
    const int f = *dflag;
    const bf16* W2 = wT + W_W2T;
    #pragma unroll 1
    for (int ni = 0; ni < 2; ++ni) {
        int nt = wv * 2 + ni;
        f32x4 acc[4] = {};
        for (int ks = 0; ks < 16; ++ks) {
            s16x8 bfrag = *(const s16x8*)(W2 + ((nt * 16 + l15) << 9) + ks * 32 + lg * 8);
            #pragma unroll
            for (int mt = 0; mt < 4; ++mt) {
                int row = mt * 16 + l15;
                s16x8 af = *(const s16x8*)(ldsH + row * 1024 + ((ks * 64 + lg * 16) ^ sw));
                acc[mt] = MFMA(af, bfrag, acc[mt]);
            }
        }
        int col = nt * 16 + l15;
        #pragma unroll
        for (int mt = 0; mt < 4; ++mt) {
            #pragma unroll
            for (int r = 0; r < 4; ++r) {
                int row = mt * 16 + lg * 4 + r;
                size_t g = (t0 + row) * Cn + col;
                float res = bf2f(xr[g]) + acc[mt][r] + P[P_B2 + col];
                if (f) ((float*)outp)[g] = res;
                else   ((bf16*)outp)[g]  = f2bf(res);
            }
        }
    }
}

extern "C" void kernel_launch(void* const* d_in, const int* in_sizes, int n_in,
                              void* d_out, int out_size, void* d_ws, size_t ws_size,
                              hipStream_t stream) {
    Ptrs ptrs;
    for (int i = 0; i < 32; ++i) ptrs.p[i] = d_in[i];

    char* base = (char*)d_ws;
    float* P    = (float*)base;                   // 8192 f32 = 32 KB
    int*  dflag = (int*)(base + 32768);
    bf16* wT    = (bf16*)(base + 33024);          // 262144 bf16 = 512 KB
    bf16* xr    = wT + 262144;                    // NE bf16 residual
    bf16* tokK  = xr + NE;
    bf16* tokV  = tokK + NE;
    bf16* tokQ  = (bf16*)d_out;                   // Q and O alias in d_out

    k_detect<<<1, 256, 0, stream>>>((const unsigned int*)d_in[0], dflag);
    k_copy<<<(int)(NE / 2048), 256, 0, stream>>>(d_in[0], dflag, xr);
    k_params<<<1, 512, 0, stream>>>(ptrs, dflag, P);
    k_tsq<<<dim3(128, 8), 128, 0, stream>>>(ptrs, dflag, wT);
    k_tmlp<<<640, 512, 0, stream>>>(ptrs, dflag, wT);
    // ---- self-attention stage ----
    k_qkv_sa<<<WNt, 256, 0, stream>>>(xr, P, wT, tokQ, tokK, tokV);
    k_attn<<<dim3(WNt, HEADS), 256, 0, stream>>>(tokQ, tokK, tokV, tokQ, P + P_RPBSA);
    k_proj<<<WNt, 256, 0, stream>>>(tokQ, P, wT + W_SAP, P_BPSA, xr);
    // ---- cross-attention stage ----
    k_qkv_ca<<<WNt, 256, 0, stream>>>(xr, d_in[1], P, wT, dflag, tokQ, tokK, tokV);
    k_attn<<<dim3(WNt, HEADS), 256, 0, stream>>>(tokQ, tokK, tokV, tokQ, P + P_RPBCA);
    k_proj<<<WNt, 256, 0, stream>>>(tokQ, P, wT + W_CAP, P_BPCA, xr);
    // ---- MLP stage ----
    k_mlp<<<(int)(NE / Cn / 64), 256, 0, stream>>>(xr, P, wT, dflag, d_out);
}

// Round 4
// 1256.389 us; speedup vs baseline: 6.6533x; 2.1952x over previous
//
#include <hip/hip_runtime.h>
#include <hip/hip_bf16.h>

typedef __hip_bfloat16 bf16;

#define Bn    4
#define NCn   3
#define Hn    112
#define Wn    112
#define Cn    128
#define HEADS 4
#define WSn   7
#define SSn   3
#define HDn   32
#define WNt   1024            // total windows = B * 16 * 16
#define Tt    147             // tokens per window = NC * 49
#define SCALE 0.17677669529663687f

static const size_t NE = (size_t)Bn * NCn * Hn * Wn * Cn; // 19,267,584

typedef float f32x4 __attribute__((ext_vector_type(4)));
typedef short s16x8 __attribute__((ext_vector_type(8)));
#define MFMA(a,b,c) __builtin_amdgcn_mfma_f32_16x16x32_bf16((a),(b),(c),0,0,0)

// P (f32 param block) offsets
#define P_QCSA 0
#define P_KCSA 384
#define P_QCCA 768
#define P_KCCA 1152
#define P_VCSA 1536
#define P_BPSA 1664
#define P_VCCA 1792
#define P_BPCA 1920
#define P_B1   2048
#define P_B2   2560
#define P_G1   2688
#define P_N1B  2816
#define P_G2   2944
#define P_N2B  3072
#define P_G3   3200
#define P_N3B  3328
#define P_RPBSA 3456
#define P_RPBCA 4132

// wT (bf16 transposed-weight block) offsets, elements
#define W_SAQ 0
#define W_SAK 16384
#define W_SAV 32768
#define W_SAP 49152
#define W_CAQ 65536
#define W_CAK 81920
#define W_CAV 98304
#define W_CAP 114688
#define W_W1T 131072
#define W_W2T 196608

struct Ptrs { const void* p[32]; };

__device__ __forceinline__ float bf2f(bf16 v) { return __bfloat162float(v); }
__device__ __forceinline__ bf16  f2bf(float v) { return __float2bfloat16(v); }
__device__ __forceinline__ short f2bs(float v) { bf16 t = __float2bfloat16(v); return *reinterpret_cast<short*>(&t); }

// dual-path input load: f==1 -> fp32, f==0 -> bf16
__device__ __forceinline__ float ldi(const void* __restrict__ p, size_t i, int f) {
    return f ? ((const float*)p)[i] : bf2f(((const bf16*)p)[i]);
}

// token (wn, t) -> flat spatial row in (B, NC, H, W) layout (after roll by -SS)
__device__ __forceinline__ int tok_row(int wn, int t) {
    int b = wn >> 8, wrem = wn & 255, wi = wrem >> 4, wj = wrem & 15;
    int n = t / 49, p = t % 49, pi = p / 7, pj = p % 7;
    int i = (wi * 7 + pi + SSn) % Hn;
    int j = (wj * 7 + pj + SSn) % Wn;
    return ((b * NCn + n) * Hn + i) * Wn + j;
}

// Detect input dtype (bf16 exponent-band heuristic)
__global__ void k_detect(const unsigned int* __restrict__ xw, int* __restrict__ flag) {
    __shared__ int cnt;
    if (threadIdx.x == 0) cnt = 0;
    __syncthreads();
    int c = 0;
    for (int i = threadIdx.x; i < 8192; i += 256) {
        unsigned e = (xw[i] >> 7) & 0xffu;
        c += (e >= 100u && e <= 140u) ? 1 : 0;
    }
    atomicAdd(&cnt, c);
    __syncthreads();
    if (threadIdx.x == 0) *flag = (cnt < 4096) ? 1 : 0;   // 1 = fp32, 0 = bf16
}

__global__ __launch_bounds__(256) void k_copy(const void* __restrict__ x,
                                              const int* __restrict__ dflag,
                                              bf16* __restrict__ xr) {
    const int f = *dflag;
    size_t i8 = ((size_t)blockIdx.x * 256 + threadIdx.x) * 8;
    s16x8 v;
    if (f) {
        const float* s = (const float*)x + i8;
        #pragma unroll
        for (int j = 0; j < 8; ++j) v[j] = f2bs(s[j]);
    } else {
        v = *(const s16x8*)((const bf16*)x + i8);
    }
    *(s16x8*)(xr + i8) = v;
}

// All scalar parameter prep: contrast-token projections, biases, LN params, rpb tables
__global__ __launch_bounds__(512) void k_params(Ptrs in, const int* __restrict__ dflag,
                                                float* __restrict__ P) {
    const int f = *dflag;
    int tid = threadIdx.x;
    if (tid < 384) {
        int n = tid >> 7, c = tid & 127;
        float aq = 0.f, ak = 0.f, aq2 = 0.f, ak2 = 0.f;
        for (int d = 0; d < Cn; ++d) {
            float ctv = ldi(in.p[2], n * Cn + d, f);
            float cev = ldi(in.p[3], n * Cn + d, f);
            aq  += ctv * ldi(in.p[10], d * Cn + c, f);
            ak  += ctv * ldi(in.p[12], d * Cn + c, f);
            aq2 += ctv * ldi(in.p[19], d * Cn + c, f);
            ak2 += cev * ldi(in.p[21], d * Cn + c, f);
        }
        P[P_QCSA + tid] = aq  + ldi(in.p[11], tid & 127, f);
        P[P_KCSA + tid] = ak  + ldi(in.p[13], tid & 127, f);
        P[P_QCCA + tid] = aq2 + ldi(in.p[20], tid & 127, f);
        P[P_KCCA + tid] = ak2 + ldi(in.p[22], tid & 127, f);
    }
    if (tid < 128) {
        P[P_VCSA + tid] = ldi(in.p[15], tid, f);
        P[P_BPSA + tid] = ldi(in.p[17], tid, f);
        P[P_VCCA + tid] = ldi(in.p[24], tid, f);
        P[P_BPCA + tid] = ldi(in.p[26], tid, f);
        P[P_B2   + tid] = ldi(in.p[31], tid, f);
        P[P_G1   + tid] = ldi(in.p[4],  tid, f);
        P[P_N1B  + tid] = ldi(in.p[5],  tid, f);
        P[P_G2   + tid] = ldi(in.p[6],  tid, f);
        P[P_N2B  + tid] = ldi(in.p[7],  tid, f);
        P[P_G3   + tid] = ldi(in.p[8],  tid, f);
        P[P_N3B  + tid] = ldi(in.p[9],  tid, f);
    }
    P[P_B1 + tid] = ldi(in.p[29], tid, f);
    for (int i = tid; i < 676; i += 512) {
        P[P_RPBSA + (i & 3) * 169 + (i >> 2)] = ldi(in.p[18], i, f);
        P[P_RPBCA + (i & 3) * 169 + (i >> 2)] = ldi(in.p[27], i, f);
    }
}

// Transpose 8 square 128x128 weights to n-major bf16
__global__ __launch_bounds__(128) void k_tsq(Ptrs in, const int* __restrict__ dflag,
                                             bf16* __restrict__ wT) {
    const int f = *dflag;
    const int map[8] = {10, 12, 14, 16, 19, 21, 23, 25};
    int mat = blockIdx.y, n = blockIdx.x, k = threadIdx.x;
    wT[mat * 16384 + n * 128 + k] = f2bf(ldi(in.p[map[mat]], k * 128 + n, f));
}

// Transpose MLP weights: w1 (128x512) -> w1t[512][128]; w2 (512x128) -> w2t[128][512]
__global__ __launch_bounds__(512) void k_tmlp(Ptrs in, const int* __restrict__ dflag,
                                              bf16* __restrict__ wT) {
    const int f = *dflag;
    int bid = blockIdx.x, tid = threadIdx.x;
    if (bid < 512) {
        if (tid < 128) wT[W_W1T + bid * 128 + tid] = f2bf(ldi(in.p[28], tid * 512 + bid, f));
    } else {
        int n = bid - 512;
        wT[W_W2T + n * 512 + tid] = f2bf(ldi(in.p[30], tid * 128 + n, f));
    }
}

// LN of one 128-wide bf16 row by one wave; bf16 result into XOR-swizzled LDS row t (stride 256B)
__device__ __forceinline__ void ln_row_swz(const bf16* __restrict__ row, int lane,
                                           const float* __restrict__ g, const float* __restrict__ b,
                                           char* __restrict__ lds, int t) {
    float a = bf2f(row[lane]), c = bf2f(row[lane + 64]);
    float s = a + c;
    #pragma unroll
    for (int off = 32; off; off >>= 1) s += __shfl_xor(s, off);
    float mean = s * (1.f / 128.f);
    float e0 = a - mean, e1 = c - mean;
    float v = e0 * e0 + e1 * e1;
    #pragma unroll
    for (int off = 32; off; off >>= 1) v += __shfl_xor(v, off);
    float rstd = rsqrtf(v * (1.f / 128.f) + 1e-5f);
    int sw = (t & 7) << 4;
    *(bf16*)(lds + t * 256 + ((lane * 2) ^ sw))        = f2bf(e0 * rstd * g[lane] + b[lane]);
    *(bf16*)(lds + t * 256 + (((lane + 64) * 2) ^ sw)) = f2bf(e1 * rstd * g[lane + 64] + b[lane + 64]);
}

// SA: gather+LN1 -> LDS, then Q/K/V = LDS @ wT via MFMA
__global__ __launch_bounds__(256) void k_qkv_sa(
    const bf16* __restrict__ xr, const float* __restrict__ P, const bf16* __restrict__ wT,
    bf16* __restrict__ tokQ, bf16* __restrict__ tokK, bf16* __restrict__ tokV) {
    __shared__ char ldsA[160 * 256];
    __shared__ int rowIdx[Tt];
    int wn = blockIdx.x, tid = threadIdx.x;
    if (tid < Tt) rowIdx[tid] = tok_row(wn, tid);
    for (int i = tid; i < 13 * 128; i += 256) ((short*)(ldsA + 147 * 256))[i] = 0;
    __syncthreads();
    int wv = tid >> 6, lane = tid & 63;
    for (int t = wv; t < Tt; t += 4)
        ln_row_swz(xr + (size_t)rowIdx[t] * Cn, lane, P + P_G1, P + P_N1B, ldsA, t);
    __syncthreads();
    int l15 = lane & 15, lg = lane >> 4, sw = (l15 & 7) << 4;
    #pragma unroll 1
    for (int mat = 0; mat < 3; ++mat) {
        const bf16* W = wT + mat * 16384;
        bf16* dst = mat == 0 ? tokQ : (mat == 1 ? tokK : tokV);
        #pragma unroll 1
        for (int ni = 0; ni < 2; ++ni) {
            int nt = wv * 2 + ni;
            f32x4 acc[10] = {};
            for (int ks = 0; ks < 4; ++ks) {
                s16x8 bfrag = *(const s16x8*)(W + ((nt * 16 + l15) << 7) + ks * 32 + lg * 8);
                #pragma unroll
                for (int mt = 0; mt < 10; ++mt) {
                    int row = mt * 16 + l15;
                    s16x8 af = *(const s16x8*)(ldsA + row * 256 + ((ks * 64 + lg * 16) ^ sw));
                    acc[mt] = MFMA(af, bfrag, acc[mt]);
                }
            }
            int col = nt * 16 + l15;
            #pragma unroll
            for (int mt = 0; mt < 10; ++mt) {
                #pragma unroll
                for (int r = 0; r < 4; ++r) {
                    int row = mt * 16 + lg * 4 + r;
                    if (row < Tt) {
                        int n = row / 49;
                        float v = acc[mt][r];
                        float o = (mat == 0) ? (v + P[P_QCSA + n * 128 + col]) * SCALE
                                : (mat == 1) ? v + P[P_KCSA + n * 128 + col]
                                             : v + P[P_VCSA + col];
                        dst[((size_t)wn * Tt + row) * Cn + col] = f2bf(o);
                    }
                }
            }
        }
    }
}

// CA: Q from LN2(xr); K/V from gathered x_kv (dual-dtype)
__global__ __launch_bounds__(256) void k_qkv_ca(
    const bf16* __restrict__ xr, const void* __restrict__ xkv,
    const float* __restrict__ P, const bf16* __restrict__ wT,
    const int* __restrict__ dflag,
    bf16* __restrict__ tokQ, bf16* __restrict__ tokK, bf16* __restrict__ tokV) {
    const int f = *dflag;
    __shared__ char ldsA[160 * 256];
    __shared__ int rowIdx[Tt];
    int wn = blockIdx.x, tid = threadIdx.x;
    if (tid < Tt) rowIdx[tid] = tok_row(wn, tid);
    for (int i = tid; i < 13 * 128; i += 256) ((short*)(ldsA + 147 * 256))[i] = 0;
    __syncthreads();
    int wv = tid >> 6, lane = tid & 63;
    for (int t = wv; t < Tt; t += 4)
        ln_row_swz(xr + (size_t)rowIdx[t] * Cn, lane, P + P_G2, P + P_N2B, ldsA, t);
    __syncthreads();
    int l15 = lane & 15, lg = lane >> 4, sw = (l15 & 7) << 4;
    // Q projection
    {
        const bf16* W = wT + W_CAQ;
        #pragma unroll 1
        for (int ni = 0; ni < 2; ++ni) {
            int nt = wv * 2 + ni;
            f32x4 acc[10] = {};
            for (int ks = 0; ks < 4; ++ks) {
                s16x8 bfrag = *(const s16x8*)(W + ((nt * 16 + l15) << 7) + ks * 32 + lg * 8);
                #pragma unroll
                for (int mt = 0; mt < 10; ++mt) {
                    int row = mt * 16 + l15;
                    s16x8 af = *(const s16x8*)(ldsA + row * 256 + ((ks * 64 + lg * 16) ^ sw));
                    acc[mt] = MFMA(af, bfrag, acc[mt]);
                }
            }
            int col = nt * 16 + l15;
            #pragma unroll
            for (int mt = 0; mt < 10; ++mt) {
                #pragma unroll
                for (int r = 0; r < 4; ++r) {
                    int row = mt * 16 + lg * 4 + r;
                    if (row < Tt) {
                        int n = row / 49;
                        tokQ[((size_t)wn * Tt + row) * Cn + col] =
                            f2bf((acc[mt][r] + P[P_QCCA + n * 128 + col]) * SCALE);
                    }
                }
            }
        }
    }
    __syncthreads();
    // gather x_kv into LDS (swizzled)
    for (int idx = tid; idx < Tt * 16; idx += 256) {
        int t = idx >> 4, c8 = idx & 15;
        s16x8 v;
        if (f) {
            const float* s = (const float*)xkv + (size_t)rowIdx[t] * Cn + c8 * 8;
            #pragma unroll
            for (int j = 0; j < 8; ++j) v[j] = f2bs(s[j]);
        } else {
            v = *(const s16x8*)((const bf16*)xkv + (size_t)rowIdx[t] * Cn + c8 * 8);
        }
        *(s16x8*)(ldsA + t * 256 + ((c8 * 16) ^ ((t & 7) << 4))) = v;
    }
    __syncthreads();
    #pragma unroll 1
    for (int mat = 0; mat < 2; ++mat) {
        const bf16* W = wT + (mat == 0 ? W_CAK : W_CAV);
        bf16* dst = mat == 0 ? tokK : tokV;
        #pragma unroll 1
        for (int ni = 0; ni < 2; ++ni) {
            int nt = wv * 2 + ni;
            f32x4 acc[10] = {};
            for (int ks = 0; ks < 4; ++ks) {
                s16x8 bfrag = *(const s16x8*)(W + ((nt * 16 + l15) << 7) + ks * 32 + lg * 8);
                #pragma unroll
                for (int mt = 0; mt < 10; ++mt) {
                    int row = mt * 16 + l15;
                    s16x8 af = *(const s16x8*)(ldsA + row * 256 + ((ks * 64 + lg * 16) ^ sw));
                    acc[mt] = MFMA(af, bfrag, acc[mt]);
                }
            }
            int col = nt * 16 + l15;
            #pragma unroll
            for (int mt = 0; mt < 10; ++mt) {
                #pragma unroll
                for (int r = 0; r < 4; ++r) {
                    int row = mt * 16 + lg * 4 + r;
                    if (row < Tt) {
                        int n = row / 49;
                        float o = (mat == 0) ? acc[mt][r] + P[P_KCCA + n * 128 + col]
                                             : acc[mt][r] + P[P_VCCA + col];
                        dst[((size_t)wn * Tt + row) * Cn + col] = f2bf(o);
                    }
                }
            }
        }
    }
}

// MFMA attention: block=(window,head), 4 waves; wave owns M-tiles {wv, wv+4, wv+8}.
// S-tile (16x160) resident in regs -> single-pass softmax; bias+mask via 49x52 BM table.
// K packed 4 rows/256B line; V transposed [32][168]; P per-wave [16][168] bf16.
__global__ __launch_bounds__(256) void k_attn(
    const bf16* __restrict__ Q, const bf16* __restrict__ K, const bf16* __restrict__ V,
    bf16* __restrict__ O, const float* __restrict__ rpbf) {
    __shared__ char ldsK[40 * 256];       // 10.0 KB  K[key][d] packed 4 keys/line
    __shared__ char ldsV[32 * 336];       // 10.5 KB  Vt[d][key], stride 336B
    __shared__ char ldsP[4 * 16 * 336];   // 21.0 KB  per-wave P[qrow][key]
    __shared__ float BM[49 * 52];         // 10.2 KB  bias+mask per (qp, kp)
    int wn = blockIdx.x, h = blockIdx.y, tid = threadIdx.x;
    int wi = (wn >> 4) & 15, wj = wn & 15;
    size_t base = (size_t)wn * Tt * Cn + h * HDn;
    // stage K (packed) and V (transposed), zero pad keys >= 147
    for (int idx = tid; idx < 640; idx += 256) {
        int key = idx >> 2, ch = idx & 3;
        s16x8 kv = {}, vv = {};
        if (key < Tt) {
            kv = *(const s16x8*)(K + base + (size_t)key * Cn + ch * 8);
            vv = *(const s16x8*)(V + base + (size_t)key * Cn + ch * 8);
        }
        *(s16x8*)(ldsK + (key >> 2) * 256 + (key & 3) * 64 + ch * 16) = kv;
        #pragma unroll
        for (int j = 0; j < 8; ++j)
            *(short*)(ldsV + (ch * 8 + j) * 336 + key * 2) = vv[j];
    }
    // build bias+mask table
    for (int idx = tid; idx < 2401; idx += 256) {
        int qp = idx / 49, kp = idx - qp * 49;
        int qpi = qp / 7, qpj = qp - qpi * 7, kpi = kp / 7, kpj = kp - kpi * 7;
        float bias = rpbf[h * 169 + (qpi - kpi + 6) * 13 + (qpj - kpj + 6)];
        int qi = wi * 7 + qpi, qj = wj * 7 + qpj, ki = wi * 7 + kpi, kj = wj * 7 + kpj;
        int rq = (qi < 105 ? 0 : (qi < 109 ? 1 : 2)) * 3 + (qj < 105 ? 0 : (qj < 109 ? 1 : 2));
        int rk = (ki < 105 ? 0 : (ki < 109 ? 1 : 2)) * 3 + (kj < 105 ? 0 : (kj < 109 ? 1 : 2));
        BM[qp * 52 + kp] = bias + (rq == rk ? 0.f : -100.f);
    }
    __syncthreads();
    int wv = tid >> 6, lane = tid & 63, l15 = lane & 15, lg = lane >> 4;
    char* myP = ldsP + wv * (16 * 336);
    for (int mt = wv; mt < 10; mt += 4) {
        int qrow = mt * 16 + l15; if (qrow > 146) qrow = 146;
        s16x8 qf = *(const s16x8*)(Q + base + (size_t)qrow * Cn + lg * 8);
        f32x4 acc[10];
        #pragma unroll
        for (int nt = 0; nt < 10; ++nt) {
            int key = nt * 16 + l15;
            s16x8 bfrag = *(const s16x8*)(ldsK + (key >> 2) * 256 + (key & 3) * 64 + lg * 16);
            f32x4 z = {};
            acc[nt] = MFMA(qf, bfrag, z);
        }
        float linv[4];
        #pragma unroll
        for (int r = 0; r < 4; ++r) {
            int row = mt * 16 + lg * 4 + r;
            int qp = row - (row >= 147 ? 147 : (row >= 98 ? 98 : (row >= 49 ? 49 : 0)));
            float s[10], m = -1e30f;
            #pragma unroll
            for (int nt = 0; nt < 10; ++nt) {
                int key = nt * 16 + l15;
                int kp = key - (key >= 147 ? 147 : (key >= 98 ? 98 : (key >= 49 ? 49 : 0)));
                float sv = acc[nt][r] + BM[qp * 52 + kp];
                if (nt == 9 && l15 >= 3) sv = -1e30f;   // pad keys 147..159
                s[nt] = sv;
                m = fmaxf(m, sv);
            }
            #pragma unroll
            for (int off = 1; off < 16; off <<= 1) m = fmaxf(m, __shfl_xor(m, off));
            float l = 0.f;
            #pragma unroll
            for (int nt = 0; nt < 10; ++nt) {
                float p = (nt == 9 && l15 >= 3) ? 0.f : __expf(s[nt] - m);
                l += p;
                *(bf16*)(myP + (lg * 4 + r) * 336 + (nt * 16 + l15) * 2) = f2bf(p);
            }
            #pragma unroll
            for (int off = 1; off < 16; off <<= 1) l += __shfl_xor(l, off);
            linv[r] = 1.f / l;
        }
        #pragma unroll
        for (int ntv = 0; ntv < 2; ++ntv) {
            f32x4 ao = {};
            #pragma unroll
            for (int ks = 0; ks < 5; ++ks) {
                s16x8 af = *(const s16x8*)(myP + l15 * 336 + ks * 64 + lg * 16);
                s16x8 vf = *(const s16x8*)(ldsV + (ntv * 16 + l15) * 336 + ks * 64 + lg * 16);
                ao = MFMA(af, vf, ao);
            }
            #pragma unroll
            for (int r = 0; r < 4; ++r) {
                int row = mt * 16 + lg * 4 + r;
                if (row < Tt)
                    O[base + (size_t)row * Cn + ntv * 16 + l15] = f2bf(ao[r] * linv[r]);
            }
        }
    }
}

// Output projection of attention (MFMA) + residual scatter-add into xr
__global__ __launch_bounds__(256) void k_proj(
    const bf16* __restrict__ tokO, const float* __restrict__ P, const bf16* __restrict__ W,
    int bpOff, bf16* __restrict__ xr) {
    __shared__ char ldsA[160 * 256];
    __shared__ int rowIdx[Tt];
    int wn = blockIdx.x, tid = threadIdx.x;
    if (tid < Tt) rowIdx[tid] = tok_row(wn, tid);
    for (int i = tid; i < 13 * 128; i += 256) ((short*)(ldsA + 147 * 256))[i] = 0;
    __syncthreads();
    for (int idx = tid; idx < Tt * 16; idx += 256) {
        int t = idx >> 4, c8 = idx & 15;
        s16x8 v = *(const s16x8*)(tokO + ((size_t)wn * Tt + t) * Cn + c8 * 8);
        *(s16x8*)(ldsA + t * 256 + ((c8 * 16) ^ ((t & 7) << 4))) = v;
    }
    __syncthreads();
    int wv = tid >> 6, lane = tid & 63;
    int l15 = lane & 15, lg = lane >> 4, sw = (l15 & 7) << 4;
    #pragma unroll 1
    for (int ni = 0; ni < 2; ++ni) {
        int nt = wv * 2 + ni;
        f32x4 acc[10] = {};
        for (int ks = 0; ks < 4; ++ks) {
            s16x8 bfrag = *(const s16x8*)(W + ((nt * 16 + l15) << 7) + ks * 32 + lg * 8);
            #pragma unroll
            for (int mt = 0; mt < 10; ++mt) {
                int row = mt * 16 + l15;
                s16x8 af = *(const s16x8*)(ldsA + row * 256 + ((ks * 64 + lg * 16) ^ sw));
                acc[mt] = MFMA(af, bfrag, acc[mt]);
            }
        }
        int col = nt * 16 + l15;
        #pragma unroll
        for (int mt = 0; mt < 10; ++mt) {
            #pragma unroll
            for (int r = 0; r < 4; ++r) {
                int row = mt * 16 + lg * 4 + r;
                if (row < Tt) {
                    size_t o = (size_t)rowIdx[row] * Cn + col;
                    xr[o] = f2bf(bf2f(xr[o]) + acc[mt][r] + P[bpOff + col]);
                }
            }
        }
    }
}

// Fused LN3 + MLP (two MFMA GEMMs, h1 in LDS) + residual; dual-dtype output store
__global__ __launch_bounds__(256) void k_mlp(
    const bf16* __restrict__ xr, const float* __restrict__ P, const bf16* __restrict__ wT,
    const int* __restrict__ dflag, void* __restrict__ outp) {
    __shared__ char ldsA[64 * 256];    // 16 KB  LN3 tile
    __shared__ char ldsH[64 * 1024];   // 64 KB  h1 tile
    int tid = threadIdx.x;
    size_t t0 = (size_t)blockIdx.x * 64;
    int wv = tid >> 6, lane = tid & 63;
    for (int t = wv; t < 64; t += 4)
        ln_row_swz(xr + (t0 + t) * Cn, lane, P + P_G3, P + P_N3B, ldsA, t);
    __syncthreads();
    int l15 = lane & 15, lg = lane >> 4, sw = (l15 & 7) << 4;
    const bf16* W1 = wT + W_W1T;
    #pragma unroll 1
    for (int ni = 0; ni < 8; ++ni) {
        int nt = wv * 8 + ni;
        f32x4 acc[4] = {};
        for (int ks = 0; ks < 4; ++ks) {
            s16x8 bfrag = *(const s16x8*)(W1 + ((nt * 16 + l15) << 7) + ks * 32 + lg * 8);
            #pragma unroll
            for (int mt = 0; mt < 4; ++mt) {
                int row = mt * 16 + l15;
                s16x8 af = *(const s16x8*)(ldsA + row * 256 + ((ks * 64 + lg * 16) ^ sw));
                acc[mt] = MFMA(af, bfrag, acc[mt]);
            }
        }
        int col = nt * 16 + l15;
        #pragma unroll
        for (int mt = 0; mt < 4; ++mt) {
            #pragma unroll
            for (int r = 0; r < 4; ++r) {
                int row = mt * 16 + lg * 4 + r;
                float v = acc[mt][r] + P[P_B1 + col];
                float g = 0.5f * v * (1.f + erff(v * 0.70710678118654752f));
                *(bf16*)(ldsH + row * 1024 + ((col * 2) ^ ((row & 7) << 4))) = f2bf(g);
            }
        }
    }
    __syncthreads();
    const int f = *dflag;
    const bf16* W2 = wT + W_W2T;
    #pragma unroll 1
    for (int ni = 0; ni < 2; ++ni) {
        int nt = wv * 2 + ni;
        f32x4 acc[4] = {};
        for (int ks = 0; ks < 16; ++ks) {
            s16x8 bfrag = *(const s16x8*)(W2 + ((nt * 16 + l15) << 9) + ks * 32 + lg * 8);
            #pragma unroll
            for (int mt = 0; mt < 4; ++mt) {
                int row = mt * 16 + l15;
                s16x8 af = *(const s16x8*)(ldsH + row * 1024 + ((ks * 64 + lg * 16) ^ sw));
                acc[mt] = MFMA(af, bfrag, acc[mt]);
            }
        }
        int col = nt * 16 + l15;
        #pragma unroll
        for (int mt = 0; mt < 4; ++mt) {
            #pragma unroll
            for (int r = 0; r < 4; ++r) {
                int row = mt * 16 + lg * 4 + r;
                size_t g = (t0 + row) * Cn + col;
                float res = bf2f(xr[g]) + acc[mt][r] + P[P_B2 + col];
                if (f) ((float*)outp)[g] = res;
                else   ((bf16*)outp)[g]  = f2bf(res);
            }
        }
    }
}

extern "C" void kernel_launch(void* const* d_in, const int* in_sizes, int n_in,
                              void* d_out, int out_size, void* d_ws, size_t ws_size,
                              hipStream_t stream) {
    Ptrs ptrs;
    for (int i = 0; i < 32; ++i) ptrs.p[i] = d_in[i];

    char* base = (char*)d_ws;
    float* P    = (float*)base;                   // 8192 f32 = 32 KB
    int*  dflag = (int*)(base + 32768);
    bf16* wT    = (bf16*)(base + 33024);          // 262144 bf16 = 512 KB
    bf16* xr    = wT + 262144;                    // NE bf16 residual
    bf16* tokK  = xr + NE;
    bf16* tokV  = tokK + NE;
    bf16* tokQ  = (bf16*)d_out;                   // Q and O alias in d_out

    k_detect<<<1, 256, 0, stream>>>((const unsigned int*)d_in[0], dflag);
    k_copy<<<(int)(NE / 2048), 256, 0, stream>>>(d_in[0], dflag, xr);
    k_params<<<1, 512, 0, stream>>>(ptrs, dflag, P);
    k_tsq<<<dim3(128, 8), 128, 0, stream>>>(ptrs, dflag, wT);
    k_tmlp<<<640, 512, 0, stream>>>(ptrs, dflag, wT);
    // ---- self-attention stage ----
    k_qkv_sa<<<WNt, 256, 0, stream>>>(xr, P, wT, tokQ, tokK, tokV);
    k_attn<<<dim3(WNt, HEADS), 256, 0, stream>>>(tokQ, tokK, tokV, tokQ, P + P_RPBSA);
    k_proj<<<WNt, 256, 0, stream>>>(tokQ, P, wT + W_SAP, P_BPSA, xr);
    // ---- cross-attention stage ----
    k_qkv_ca<<<WNt, 256, 0, stream>>>(xr, d_in[1], P, wT, dflag, tokQ, tokK, tokV);
    k_attn<<<dim3(WNt, HEADS), 256, 0, stream>>>(tokQ, tokK, tokV, tokQ, P + P_RPBCA);
    k_proj<<<WNt, 256, 0, stream>>>(tokQ, P, wT + W_CAP, P_BPCA, xr);
    // ---- MLP stage ----
    k_mlp<<<(int)(NE / Cn / 64), 256, 0, stream>>>(xr, P, wT, dflag, d_out);
}

// Round 5
// 1071.426 us; speedup vs baseline: 7.8019x; 1.1726x over previous
//
#include <hip/hip_runtime.h>
#include <hip/hip_bf16.h>

typedef __hip_bfloat16 bf16;

#define Bn    4
#define NCn   3
#define Hn    112
#define Wn    112
#define Cn    128
#define HEADS 4
#define WSn   7
#define SSn   3
#define HDn   32
#define WNt   1024            // total windows = B * 16 * 16
#define Tt    147             // tokens per window = NC * 49
#define SCALE 0.17677669529663687f

// LDS strides: 272B (A tiles), 1040B (h1): row*stride rotates bank quad per row
#define SA    272
#define SH    1040

static const size_t NE = (size_t)Bn * NCn * Hn * Wn * Cn; // 19,267,584

typedef float f32x4 __attribute__((ext_vector_type(4)));
typedef short s16x8 __attribute__((ext_vector_type(8)));
#define MFMA(a,b,c) __builtin_amdgcn_mfma_f32_16x16x32_bf16((a),(b),(c),0,0,0)

// P (f32 param block) offsets
#define P_QCSA 0
#define P_KCSA 384
#define P_QCCA 768
#define P_KCCA 1152
#define P_VCSA 1536
#define P_BPSA 1664
#define P_VCCA 1792
#define P_BPCA 1920
#define P_B1   2048
#define P_B2   2560
#define P_G1   2688
#define P_N1B  2816
#define P_G2   2944
#define P_N2B  3072
#define P_G3   3200
#define P_N3B  3328
#define P_RPBSA 3456
#define P_RPBCA 4132

// wT (bf16 packed-fragment weights) offsets, elements.
// Packed layout per matrix: [(ntile*KS + ks)*64 + lane]*8, element j ->
//   n = ntile*16 + (lane&15), k = ks*32 + (lane>>4)*8 + j
#define W_SAQ 0
#define W_SAK 16384
#define W_SAV 32768
#define W_SAP 49152
#define W_CAQ 65536
#define W_CAK 81920
#define W_CAV 98304
#define W_CAP 114688
#define W_W1T 131072
#define W_W2T 196608

struct Ptrs { const void* p[32]; };

__device__ __forceinline__ float bf2f(bf16 v) { return __bfloat162float(v); }
__device__ __forceinline__ bf16  f2bf(float v) { return __float2bfloat16(v); }
__device__ __forceinline__ short f2bs(float v) { bf16 t = __float2bfloat16(v); return *reinterpret_cast<short*>(&t); }

// dual-path input load: f==1 -> fp32, f==0 -> bf16
__device__ __forceinline__ float ldi(const void* __restrict__ p, size_t i, int f) {
    return f ? ((const float*)p)[i] : bf2f(((const bf16*)p)[i]);
}

// token (wn, t) -> flat spatial row in (B, NC, H, W) layout (after roll by -SS)
__device__ __forceinline__ int tok_row(int wn, int t) {
    int b = wn >> 8, wrem = wn & 255, wi = wrem >> 4, wj = wrem & 15;
    int n = t / 49, p = t % 49, pi = p / 7, pj = p % 7;
    int i = (wi * 7 + pi + SSn) % Hn;
    int j = (wj * 7 + pj + SSn) % Wn;
    return ((b * NCn + n) * Hn + i) * Wn + j;
}

// Detect input dtype (bf16 exponent-band heuristic)
__global__ void k_detect(const unsigned int* __restrict__ xw, int* __restrict__ flag) {
    __shared__ int cnt;
    if (threadIdx.x == 0) cnt = 0;
    __syncthreads();
    int c = 0;
    for (int i = threadIdx.x; i < 8192; i += 256) {
        unsigned e = (xw[i] >> 7) & 0xffu;
        c += (e >= 100u && e <= 140u) ? 1 : 0;
    }
    atomicAdd(&cnt, c);
    __syncthreads();
    if (threadIdx.x == 0) *flag = (cnt < 4096) ? 1 : 0;   // 1 = fp32, 0 = bf16
}

__global__ __launch_bounds__(256) void k_copy(const void* __restrict__ x,
                                              const int* __restrict__ dflag,
                                              bf16* __restrict__ xr) {
    const int f = *dflag;
    size_t i8 = ((size_t)blockIdx.x * 256 + threadIdx.x) * 8;
    s16x8 v;
    if (f) {
        const float* s = (const float*)x + i8;
        #pragma unroll
        for (int j = 0; j < 8; ++j) v[j] = f2bs(s[j]);
    } else {
        v = *(const s16x8*)((const bf16*)x + i8);
    }
    *(s16x8*)(xr + i8) = v;
}

// All scalar parameter prep: contrast-token projections, biases, LN params, rpb tables
__global__ __launch_bounds__(512) void k_params(Ptrs in, const int* __restrict__ dflag,
                                                float* __restrict__ P) {
    const int f = *dflag;
    int tid = threadIdx.x;
    if (tid < 384) {
        int n = tid >> 7, c = tid & 127;
        float aq = 0.f, ak = 0.f, aq2 = 0.f, ak2 = 0.f;
        for (int d = 0; d < Cn; ++d) {
            float ctv = ldi(in.p[2], n * Cn + d, f);
            float cev = ldi(in.p[3], n * Cn + d, f);
            aq  += ctv * ldi(in.p[10], d * Cn + c, f);
            ak  += ctv * ldi(in.p[12], d * Cn + c, f);
            aq2 += ctv * ldi(in.p[19], d * Cn + c, f);
            ak2 += cev * ldi(in.p[21], d * Cn + c, f);
        }
        P[P_QCSA + tid] = aq  + ldi(in.p[11], tid & 127, f);
        P[P_KCSA + tid] = ak  + ldi(in.p[13], tid & 127, f);
        P[P_QCCA + tid] = aq2 + ldi(in.p[20], tid & 127, f);
        P[P_KCCA + tid] = ak2 + ldi(in.p[22], tid & 127, f);
    }
    if (tid < 128) {
        P[P_VCSA + tid] = ldi(in.p[15], tid, f);
        P[P_BPSA + tid] = ldi(in.p[17], tid, f);
        P[P_VCCA + tid] = ldi(in.p[24], tid, f);
        P[P_BPCA + tid] = ldi(in.p[26], tid, f);
        P[P_B2   + tid] = ldi(in.p[31], tid, f);
        P[P_G1   + tid] = ldi(in.p[4],  tid, f);
        P[P_N1B  + tid] = ldi(in.p[5],  tid, f);
        P[P_G2   + tid] = ldi(in.p[6],  tid, f);
        P[P_N2B  + tid] = ldi(in.p[7],  tid, f);
        P[P_G3   + tid] = ldi(in.p[8],  tid, f);
        P[P_N3B  + tid] = ldi(in.p[9],  tid, f);
    }
    P[P_B1 + tid] = ldi(in.p[29], tid, f);
    for (int i = tid; i < 676; i += 512) {
        P[P_RPBSA + (i & 3) * 169 + (i >> 2)] = ldi(in.p[18], i, f);
        P[P_RPBCA + (i & 3) * 169 + (i >> 2)] = ldi(in.p[27], i, f);
    }
}

// Pack 8 square 128x128 weights into MFMA-fragment order.
// grid (32, 8): x = ntile*4+ks, y = mat; block 64 lanes.
__global__ __launch_bounds__(64) void k_tsq(Ptrs in, const int* __restrict__ dflag,
                                            bf16* __restrict__ wT) {
    const int f = *dflag;
    const int map[8] = {10, 12, 14, 16, 19, 21, 23, 25};
    int mat = blockIdx.y, ntks = blockIdx.x, lane = threadIdx.x;
    int ntile = ntks >> 2, ks = ntks & 3;
    int n = ntile * 16 + (lane & 15), k0 = ks * 32 + (lane >> 4) * 8;
    const void* src = in.p[map[mat]];
    s16x8 v;
    #pragma unroll
    for (int j = 0; j < 8; ++j) v[j] = f2bs(ldi(src, (size_t)(k0 + j) * 128 + n, f));
    *(s16x8*)(wT + mat * 16384 + ((size_t)ntks * 64 + lane) * 8) = v;
}

// Pack MLP weights: w1 (128x512): 128 blocks (ntile*4+ks); w2 (512x128): 128 blocks (ntile*16+ks)
__global__ __launch_bounds__(64) void k_tmlp(Ptrs in, const int* __restrict__ dflag,
                                             bf16* __restrict__ wT) {
    const int f = *dflag;
    int bid = blockIdx.x, lane = threadIdx.x;
    s16x8 v;
    if (bid < 128) {
        int ntile = bid >> 2, ks = bid & 3;
        int n = ntile * 16 + (lane & 15), k0 = ks * 32 + (lane >> 4) * 8;
        #pragma unroll
        for (int j = 0; j < 8; ++j) v[j] = f2bs(ldi(in.p[28], (size_t)(k0 + j) * 512 + n, f));
        *(s16x8*)(wT + W_W1T + ((size_t)bid * 64 + lane) * 8) = v;
    } else {
        int b2 = bid - 128;
        int ntile = b2 >> 4, ks = b2 & 15;
        int n = ntile * 16 + (lane & 15), k0 = ks * 32 + (lane >> 4) * 8;
        #pragma unroll
        for (int j = 0; j < 8; ++j) v[j] = f2bs(ldi(in.p[30], (size_t)(k0 + j) * 128 + n, f));
        *(s16x8*)(wT + W_W2T + ((size_t)b2 * 64 + lane) * 8) = v;
    }
}

// LN of one 128-wide bf16 row by one wave; bf16 result into LDS at stride-SA row
__device__ __forceinline__ void ln_row(const bf16* __restrict__ row, int lane,
                                       const float* __restrict__ g, const float* __restrict__ b,
                                       char* __restrict__ dst) {
    float a = bf2f(row[lane]), c = bf2f(row[lane + 64]);
    float s = a + c;
    #pragma unroll
    for (int off = 32; off; off >>= 1) s += __shfl_xor(s, off);
    float mean = s * (1.f / 128.f);
    float e0 = a - mean, e1 = c - mean;
    float v = e0 * e0 + e1 * e1;
    #pragma unroll
    for (int off = 32; off; off >>= 1) v += __shfl_xor(v, off);
    float rstd = rsqrtf(v * (1.f / 128.f) + 1e-5f);
    *(bf16*)(dst + lane * 2)        = f2bf(e0 * rstd * g[lane] + b[lane]);
    *(bf16*)(dst + (lane + 64) * 2) = f2bf(e1 * rstd * g[lane + 64] + b[lane + 64]);
}

// SA: gather+LN1 -> LDS, then Q/K/V = LDS @ wT via MFMA (packed weights)
__global__ __launch_bounds__(256) void k_qkv_sa(
    const bf16* __restrict__ xr, const float* __restrict__ P, const bf16* __restrict__ wT,
    bf16* __restrict__ tokQ, bf16* __restrict__ tokK, bf16* __restrict__ tokV) {
    __shared__ char ldsA[160 * SA];
    __shared__ int rowIdx[Tt];
    int wn = blockIdx.x, tid = threadIdx.x;
    if (tid < Tt) rowIdx[tid] = tok_row(wn, tid);
    for (int i = tid; i < 13 * SA / 4; i += 256) ((int*)(ldsA + 147 * SA))[i] = 0;
    __syncthreads();
    int wv = tid >> 6, lane = tid & 63;
    for (int t = wv; t < Tt; t += 4)
        ln_row(xr + (size_t)rowIdx[t] * Cn, lane, P + P_G1, P + P_N1B, ldsA + t * SA);
    __syncthreads();
    int l15 = lane & 15, lg = lane >> 4;
    #pragma unroll 1
    for (int mat = 0; mat < 3; ++mat) {
        const bf16* W = wT + mat * 16384;
        bf16* dst = mat == 0 ? tokQ : (mat == 1 ? tokK : tokV);
        #pragma unroll 1
        for (int ni = 0; ni < 2; ++ni) {
            int nt = wv * 2 + ni;
            f32x4 acc[10] = {};
            #pragma unroll
            for (int ks = 0; ks < 4; ++ks) {
                s16x8 bfrag = *(const s16x8*)(W + (((nt << 2) + ks) * 64 + lane) * 8);
                #pragma unroll
                for (int mt = 0; mt < 10; ++mt) {
                    s16x8 af = *(const s16x8*)(ldsA + (mt * 16 + l15) * SA + ks * 64 + lg * 16);
                    acc[mt] = MFMA(af, bfrag, acc[mt]);
                }
            }
            int col = nt * 16 + l15;
            #pragma unroll
            for (int mt = 0; mt < 10; ++mt) {
                #pragma unroll
                for (int r = 0; r < 4; ++r) {
                    int row = mt * 16 + lg * 4 + r;
                    if (row < Tt) {
                        int n = row / 49;
                        float v = acc[mt][r];
                        float o = (mat == 0) ? (v + P[P_QCSA + n * 128 + col]) * SCALE
                                : (mat == 1) ? v + P[P_KCSA + n * 128 + col]
                                             : v + P[P_VCSA + col];
                        dst[((size_t)wn * Tt + row) * Cn + col] = f2bf(o);
                    }
                }
            }
        }
    }
}

// CA: Q from LN2(xr); K/V from gathered x_kv (dual-dtype); packed weights
__global__ __launch_bounds__(256) void k_qkv_ca(
    const bf16* __restrict__ xr, const void* __restrict__ xkv,
    const float* __restrict__ P, const bf16* __restrict__ wT,
    const int* __restrict__ dflag,
    bf16* __restrict__ tokQ, bf16* __restrict__ tokK, bf16* __restrict__ tokV) {
    const int f = *dflag;
    __shared__ char ldsA[160 * SA];
    __shared__ int rowIdx[Tt];
    int wn = blockIdx.x, tid = threadIdx.x;
    if (tid < Tt) rowIdx[tid] = tok_row(wn, tid);
    for (int i = tid; i < 13 * SA / 4; i += 256) ((int*)(ldsA + 147 * SA))[i] = 0;
    __syncthreads();
    int wv = tid >> 6, lane = tid & 63;
    for (int t = wv; t < Tt; t += 4)
        ln_row(xr + (size_t)rowIdx[t] * Cn, lane, P + P_G2, P + P_N2B, ldsA + t * SA);
    __syncthreads();
    int l15 = lane & 15, lg = lane >> 4;
    // Q projection
    {
        const bf16* W = wT + W_CAQ;
        #pragma unroll 1
        for (int ni = 0; ni < 2; ++ni) {
            int nt = wv * 2 + ni;
            f32x4 acc[10] = {};
            #pragma unroll
            for (int ks = 0; ks < 4; ++ks) {
                s16x8 bfrag = *(const s16x8*)(W + (((nt << 2) + ks) * 64 + lane) * 8);
                #pragma unroll
                for (int mt = 0; mt < 10; ++mt) {
                    s16x8 af = *(const s16x8*)(ldsA + (mt * 16 + l15) * SA + ks * 64 + lg * 16);
                    acc[mt] = MFMA(af, bfrag, acc[mt]);
                }
            }
            int col = nt * 16 + l15;
            #pragma unroll
            for (int mt = 0; mt < 10; ++mt) {
                #pragma unroll
                for (int r = 0; r < 4; ++r) {
                    int row = mt * 16 + lg * 4 + r;
                    if (row < Tt) {
                        int n = row / 49;
                        tokQ[((size_t)wn * Tt + row) * Cn + col] =
                            f2bf((acc[mt][r] + P[P_QCCA + n * 128 + col]) * SCALE);
                    }
                }
            }
        }
    }
    __syncthreads();
    // gather x_kv into LDS
    for (int idx = tid; idx < Tt * 16; idx += 256) {
        int t = idx >> 4, c8 = idx & 15;
        s16x8 v;
        if (f) {
            const float* s = (const float*)xkv + (size_t)rowIdx[t] * Cn + c8 * 8;
            #pragma unroll
            for (int j = 0; j < 8; ++j) v[j] = f2bs(s[j]);
        } else {
            v = *(const s16x8*)((const bf16*)xkv + (size_t)rowIdx[t] * Cn + c8 * 8);
        }
        *(s16x8*)(ldsA + t * SA + c8 * 16) = v;
    }
    __syncthreads();
    #pragma unroll 1
    for (int mat = 0; mat < 2; ++mat) {
        const bf16* W = wT + (mat == 0 ? W_CAK : W_CAV);
        bf16* dst = mat == 0 ? tokK : tokV;
        #pragma unroll 1
        for (int ni = 0; ni < 2; ++ni) {
            int nt = wv * 2 + ni;
            f32x4 acc[10] = {};
            #pragma unroll
            for (int ks = 0; ks < 4; ++ks) {
                s16x8 bfrag = *(const s16x8*)(W + (((nt << 2) + ks) * 64 + lane) * 8);
                #pragma unroll
                for (int mt = 0; mt < 10; ++mt) {
                    s16x8 af = *(const s16x8*)(ldsA + (mt * 16 + l15) * SA + ks * 64 + lg * 16);
                    acc[mt] = MFMA(af, bfrag, acc[mt]);
                }
            }
            int col = nt * 16 + l15;
            #pragma unroll
            for (int mt = 0; mt < 10; ++mt) {
                #pragma unroll
                for (int r = 0; r < 4; ++r) {
                    int row = mt * 16 + lg * 4 + r;
                    if (row < Tt) {
                        int n = row / 49;
                        float o = (mat == 0) ? acc[mt][r] + P[P_KCCA + n * 128 + col]
                                             : acc[mt][r] + P[P_VCCA + col];
                        dst[((size_t)wn * Tt + row) * Cn + col] = f2bf(o);
                    }
                }
            }
        }
    }
}

// MFMA attention: block=(window,head), 4 waves; wave owns M-tiles {wv, wv+4, wv+8}.
__global__ __launch_bounds__(256) void k_attn(
    const bf16* __restrict__ Q, const bf16* __restrict__ K, const bf16* __restrict__ V,
    bf16* __restrict__ O, const float* __restrict__ rpbf) {
    __shared__ char ldsK[40 * 256];       // 10.0 KB  K[key][d] packed 4 keys/line
    __shared__ char ldsV[32 * 336];       // 10.5 KB  Vt[d][key], stride 336B
    __shared__ char ldsP[4 * 16 * 336];   // 21.0 KB  per-wave P[qrow][key]
    __shared__ float BM[49 * 52];         // 10.2 KB  bias+mask per (qp, kp)
    int wn = blockIdx.x, h = blockIdx.y, tid = threadIdx.x;
    int wi = (wn >> 4) & 15, wj = wn & 15;
    size_t base = (size_t)wn * Tt * Cn + h * HDn;
    for (int idx = tid; idx < 640; idx += 256) {
        int key = idx >> 2, ch = idx & 3;
        s16x8 kv = {}, vv = {};
        if (key < Tt) {
            kv = *(const s16x8*)(K + base + (size_t)key * Cn + ch * 8);
            vv = *(const s16x8*)(V + base + (size_t)key * Cn + ch * 8);
        }
        *(s16x8*)(ldsK + (key >> 2) * 256 + (key & 3) * 64 + ch * 16) = kv;
        #pragma unroll
        for (int j = 0; j < 8; ++j)
            *(short*)(ldsV + (ch * 8 + j) * 336 + key * 2) = vv[j];
    }
    for (int idx = tid; idx < 2401; idx += 256) {
        int qp = idx / 49, kp = idx - qp * 49;
        int qpi = qp / 7, qpj = qp - qpi * 7, kpi = kp / 7, kpj = kp - kpi * 7;
        float bias = rpbf[h * 169 + (qpi - kpi + 6) * 13 + (qpj - kpj + 6)];
        int qi = wi * 7 + qpi, qj = wj * 7 + qpj, ki = wi * 7 + kpi, kj = wj * 7 + kpj;
        int rq = (qi < 105 ? 0 : (qi < 109 ? 1 : 2)) * 3 + (qj < 105 ? 0 : (qj < 109 ? 1 : 2));
        int rk = (ki < 105 ? 0 : (ki < 109 ? 1 : 2)) * 3 + (kj < 105 ? 0 : (kj < 109 ? 1 : 2));
        BM[qp * 52 + kp] = bias + (rq == rk ? 0.f : -100.f);
    }
    __syncthreads();
    int wv = tid >> 6, lane = tid & 63, l15 = lane & 15, lg = lane >> 4;
    char* myP = ldsP + wv * (16 * 336);
    for (int mt = wv; mt < 10; mt += 4) {
        int qrow = mt * 16 + l15; if (qrow > 146) qrow = 146;
        s16x8 qf = *(const s16x8*)(Q + base + (size_t)qrow * Cn + lg * 8);
        f32x4 acc[10];
        #pragma unroll
        for (int nt = 0; nt < 10; ++nt) {
            int key = nt * 16 + l15;
            s16x8 bfrag = *(const s16x8*)(ldsK + (key >> 2) * 256 + (key & 3) * 64 + lg * 16);
            f32x4 z = {};
            acc[nt] = MFMA(qf, bfrag, z);
        }
        float linv[4];
        #pragma unroll
        for (int r = 0; r < 4; ++r) {
            int row = mt * 16 + lg * 4 + r;
            int qp = row - (row >= 147 ? 147 : (row >= 98 ? 98 : (row >= 49 ? 49 : 0)));
            float s[10], m = -1e30f;
            #pragma unroll
            for (int nt = 0; nt < 10; ++nt) {
                int key = nt * 16 + l15;
                int kp = key - (key >= 147 ? 147 : (key >= 98 ? 98 : (key >= 49 ? 49 : 0)));
                float sv = acc[nt][r] + BM[qp * 52 + kp];
                if (nt == 9 && l15 >= 3) sv = -1e30f;
                s[nt] = sv;
                m = fmaxf(m, sv);
            }
            #pragma unroll
            for (int off = 1; off < 16; off <<= 1) m = fmaxf(m, __shfl_xor(m, off));
            float l = 0.f;
            #pragma unroll
            for (int nt = 0; nt < 10; ++nt) {
                float p = (nt == 9 && l15 >= 3) ? 0.f : __expf(s[nt] - m);
                l += p;
                *(bf16*)(myP + (lg * 4 + r) * 336 + (nt * 16 + l15) * 2) = f2bf(p);
            }
            #pragma unroll
            for (int off = 1; off < 16; off <<= 1) l += __shfl_xor(l, off);
            linv[r] = 1.f / l;
        }
        #pragma unroll
        for (int ntv = 0; ntv < 2; ++ntv) {
            f32x4 ao = {};
            #pragma unroll
            for (int ks = 0; ks < 5; ++ks) {
                s16x8 af = *(const s16x8*)(myP + l15 * 336 + ks * 64 + lg * 16);
                s16x8 vf = *(const s16x8*)(ldsV + (ntv * 16 + l15) * 336 + ks * 64 + lg * 16);
                ao = MFMA(af, vf, ao);
            }
            #pragma unroll
            for (int r = 0; r < 4; ++r) {
                int row = mt * 16 + lg * 4 + r;
                if (row < Tt)
                    O[base + (size_t)row * Cn + ntv * 16 + l15] = f2bf(ao[r] * linv[r]);
            }
        }
    }
}

// Output projection of attention (MFMA, packed weights) + residual scatter-add into xr
__global__ __launch_bounds__(256) void k_proj(
    const bf16* __restrict__ tokO, const float* __restrict__ P, const bf16* __restrict__ W,
    int bpOff, bf16* __restrict__ xr) {
    __shared__ char ldsA[160 * SA];
    __shared__ int rowIdx[Tt];
    int wn = blockIdx.x, tid = threadIdx.x;
    if (tid < Tt) rowIdx[tid] = tok_row(wn, tid);
    for (int i = tid; i < 13 * SA / 4; i += 256) ((int*)(ldsA + 147 * SA))[i] = 0;
    __syncthreads();
    for (int idx = tid; idx < Tt * 16; idx += 256) {
        int t = idx >> 4, c8 = idx & 15;
        s16x8 v = *(const s16x8*)(tokO + ((size_t)wn * Tt + t) * Cn + c8 * 8);
        *(s16x8*)(ldsA + t * SA + c8 * 16) = v;
    }
    __syncthreads();
    int wv = tid >> 6, lane = tid & 63;
    int l15 = lane & 15, lg = lane >> 4;
    #pragma unroll 1
    for (int ni = 0; ni < 2; ++ni) {
        int nt = wv * 2 + ni;
        f32x4 acc[10] = {};
        #pragma unroll
        for (int ks = 0; ks < 4; ++ks) {
            s16x8 bfrag = *(const s16x8*)(W + (((nt << 2) + ks) * 64 + lane) * 8);
            #pragma unroll
            for (int mt = 0; mt < 10; ++mt) {
                s16x8 af = *(const s16x8*)(ldsA + (mt * 16 + l15) * SA + ks * 64 + lg * 16);
                acc[mt] = MFMA(af, bfrag, acc[mt]);
            }
        }
        int col = nt * 16 + l15;
        #pragma unroll
        for (int mt = 0; mt < 10; ++mt) {
            #pragma unroll
            for (int r = 0; r < 4; ++r) {
                int row = mt * 16 + lg * 4 + r;
                if (row < Tt) {
                    size_t o = (size_t)rowIdx[row] * Cn + col;
                    xr[o] = f2bf(bf2f(xr[o]) + acc[mt][r] + P[bpOff + col]);
                }
            }
        }
    }
}

// Fused LN3 + MLP: 32-token tile, packed weights double-buffered, conflict-free LDS
__global__ __launch_bounds__(256) void k_mlp(
    const bf16* __restrict__ xr, const float* __restrict__ P, const bf16* __restrict__ wT,
    const int* __restrict__ dflag, void* __restrict__ outp) {
    __shared__ char ldsA[32 * SA];     // 8.5 KB  LN3 tile
    __shared__ char ldsH[32 * SH];     // 32.5 KB h1 tile
    int tid = threadIdx.x;
    size_t t0 = (size_t)blockIdx.x * 32;
    int wv = tid >> 6, lane = tid & 63;
    for (int t = wv; t < 32; t += 4)
        ln_row(xr + (t0 + t) * Cn, lane, P + P_G3, P + P_N3B, ldsA + t * SA);
    __syncthreads();
    int l15 = lane & 15, lg = lane >> 4;
    const bf16* W1 = wT + W_W1T;
    // GEMM1: wave computes 8 n-tiles (128 cols), double-buffered weight frags
    {
        int nt0 = wv * 8;
        s16x8 bc0, bc1, bc2, bc3;
        bc0 = *(const s16x8*)(W1 + (((nt0 << 2) + 0) * 64 + lane) * 8);
        bc1 = *(const s16x8*)(W1 + (((nt0 << 2) + 1) * 64 + lane) * 8);
        bc2 = *(const s16x8*)(W1 + (((nt0 << 2) + 2) * 64 + lane) * 8);
        bc3 = *(const s16x8*)(W1 + (((nt0 << 2) + 3) * 64 + lane) * 8);
        #pragma unroll 1
        for (int ni = 0; ni < 8; ++ni) {
            int nt = nt0 + ni;
            s16x8 bn0, bn1, bn2, bn3;
            // prefetch next n-tile (ni==7 reads harmlessly into adjacent wT region)
            bn0 = *(const s16x8*)(W1 + ((((nt + 1) << 2) + 0) * 64 + lane) * 8);
            bn1 = *(const s16x8*)(W1 + ((((nt + 1) << 2) + 1) * 64 + lane) * 8);
            bn2 = *(const s16x8*)(W1 + ((((nt + 1) << 2) + 2) * 64 + lane) * 8);
            bn3 = *(const s16x8*)(W1 + ((((nt + 1) << 2) + 3) * 64 + lane) * 8);
            f32x4 acc0 = {}, acc1 = {};
            s16x8 af;
            af = *(const s16x8*)(ldsA + l15 * SA + 0 * 64 + lg * 16);        acc0 = MFMA(af, bc0, acc0);
            af = *(const s16x8*)(ldsA + (16 + l15) * SA + 0 * 64 + lg * 16); acc1 = MFMA(af, bc0, acc1);
            af = *(const s16x8*)(ldsA + l15 * SA + 1 * 64 + lg * 16);        acc0 = MFMA(af, bc1, acc0);
            af = *(const s16x8*)(ldsA + (16 + l15) * SA + 1 * 64 + lg * 16); acc1 = MFMA(af, bc1, acc1);
            af = *(const s16x8*)(ldsA + l15 * SA + 2 * 64 + lg * 16);        acc0 = MFMA(af, bc2, acc0);
            af = *(const s16x8*)(ldsA + (16 + l15) * SA + 2 * 64 + lg * 16); acc1 = MFMA(af, bc2, acc1);
            af = *(const s16x8*)(ldsA + l15 * SA + 3 * 64 + lg * 16);        acc0 = MFMA(af, bc3, acc0);
            af = *(const s16x8*)(ldsA + (16 + l15) * SA + 3 * 64 + lg * 16); acc1 = MFMA(af, bc3, acc1);
            int col = nt * 16 + l15;
            float b1v = P[P_B1 + col];
            #pragma unroll
            for (int r = 0; r < 4; ++r) {
                int row0 = lg * 4 + r;
                float v0 = acc0[r] + b1v;
                float g0 = 0.5f * v0 * (1.f + erff(v0 * 0.70710678118654752f));
                *(bf16*)(ldsH + row0 * SH + col * 2) = f2bf(g0);
                float v1 = acc1[r] + b1v;
                float g1 = 0.5f * v1 * (1.f + erff(v1 * 0.70710678118654752f));
                *(bf16*)(ldsH + (16 + row0) * SH + col * 2) = f2bf(g1);
            }
            bc0 = bn0; bc1 = bn1; bc2 = bn2; bc3 = bn3;
        }
    }
    __syncthreads();
    const int f = *dflag;
    const bf16* W2 = wT + W_W2T;
    #pragma unroll 1
    for (int ni = 0; ni < 2; ++ni) {
        int nt = wv * 2 + ni;
        f32x4 acc0 = {}, acc1 = {};
        s16x8 bc = *(const s16x8*)(W2 + (((nt << 4) + 0) * 64 + lane) * 8);
        #pragma unroll 1
        for (int ks = 0; ks < 16; ++ks) {
            s16x8 bn = *(const s16x8*)(W2 + (((nt << 4) + ks + 1) * 64 + lane) * 8);
            s16x8 af;
            af = *(const s16x8*)(ldsH + l15 * SH + ks * 64 + lg * 16);        acc0 = MFMA(af, bc, acc0);
            af = *(const s16x8*)(ldsH + (16 + l15) * SH + ks * 64 + lg * 16); acc1 = MFMA(af, bc, acc1);
            bc = bn;
        }
        int col = nt * 16 + l15;
        float b2v = P[P_B2 + col];
        #pragma unroll
        for (int r = 0; r < 4; ++r) {
            int row0 = lg * 4 + r;
            size_t g0 = (t0 + row0) * Cn + col;
            float res0 = bf2f(xr[g0]) + acc0[r] + b2v;
            size_t g1 = (t0 + 16 + row0) * Cn + col;
            float res1 = bf2f(xr[g1]) + acc1[r] + b2v;
            if (f) { ((float*)outp)[g0] = res0; ((float*)outp)[g1] = res1; }
            else   { ((bf16*)outp)[g0]  = f2bf(res0); ((bf16*)outp)[g1] = f2bf(res1); }
        }
    }
}

extern "C" void kernel_launch(void* const* d_in, const int* in_sizes, int n_in,
                              void* d_out, int out_size, void* d_ws, size_t ws_size,
                              hipStream_t stream) {
    Ptrs ptrs;
    for (int i = 0; i < 32; ++i) ptrs.p[i] = d_in[i];

    char* base = (char*)d_ws;
    float* P    = (float*)base;                   // 8192 f32 = 32 KB
    int*  dflag = (int*)(base + 32768);
    bf16* wT    = (bf16*)(base + 33024);          // 262144 bf16 = 512 KB
    bf16* xr    = wT + 262144;                    // NE bf16 residual
    bf16* tokK  = xr + NE;
    bf16* tokV  = tokK + NE;
    bf16* tokQ  = (bf16*)d_out;                   // Q and O alias in d_out

    k_detect<<<1, 256, 0, stream>>>((const unsigned int*)d_in[0], dflag);
    k_copy<<<(int)(NE / 2048), 256, 0, stream>>>(d_in[0], dflag, xr);
    k_params<<<1, 512, 0, stream>>>(ptrs, dflag, P);
    k_tsq<<<dim3(32, 8), 64, 0, stream>>>(ptrs, dflag, wT);
    k_tmlp<<<256, 64, 0, stream>>>(ptrs, dflag, wT);
    // ---- self-attention stage ----
    k_qkv_sa<<<WNt, 256, 0, stream>>>(xr, P, wT, tokQ, tokK, tokV);
    k_attn<<<dim3(WNt, HEADS), 256, 0, stream>>>(tokQ, tokK, tokV, tokQ, P + P_RPBSA);
    k_proj<<<WNt, 256, 0, stream>>>(tokQ, P, wT + W_SAP, P_BPSA, xr);
    // ---- cross-attention stage ----
    k_qkv_ca<<<WNt, 256, 0, stream>>>(xr, d_in[1], P, wT, dflag, tokQ, tokK, tokV);
    k_attn<<<dim3(WNt, HEADS), 256, 0, stream>>>(tokQ, tokK, tokV, tokQ, P + P_RPBCA);
    k_proj<<<WNt, 256, 0, stream>>>(tokQ, P, wT + W_CAP, P_BPCA, xr);
    // ---- MLP stage ----
    k_mlp<<<(int)(NE / Cn / 32), 256, 0, stream>>>(xr, P, wT, dflag, d_out);
}

// Round 6
// 740.972 us; speedup vs baseline: 11.2813x; 1.4460x over previous
//
#include <hip/hip_runtime.h>
#include <hip/hip_bf16.h>

typedef __hip_bfloat16 bf16;

#define Bn    4
#define NCn   3
#define Hn    112
#define Wn    112
#define Cn    128
#define HEADS 4
#define WSn   7
#define SSn   3
#define HDn   32
#define WNt   1024            // total windows = B * 16 * 16
#define Tt    147             // tokens per window = NC * 49
#define SCALE 0.17677669529663687f

// LDS stride for A tiles: 272B rotates bank quad per row
#define SA    272
#define SH    1040

static const size_t NE = (size_t)Bn * NCn * Hn * Wn * Cn; // 19,267,584

typedef float f32x4 __attribute__((ext_vector_type(4)));
typedef short s16x8 __attribute__((ext_vector_type(8)));
typedef short s16x4 __attribute__((ext_vector_type(4)));
#define MFMA(a,b,c) __builtin_amdgcn_mfma_f32_16x16x32_bf16((a),(b),(c),0,0,0)

// P (f32 param block) offsets
#define P_QCSA 0
#define P_KCSA 384
#define P_QCCA 768
#define P_KCCA 1152
#define P_VCSA 1536
#define P_BPSA 1664
#define P_VCCA 1792
#define P_BPCA 1920
#define P_B1   2048
#define P_B2   2560
#define P_G1   2688
#define P_N1B  2816
#define P_G2   2944
#define P_N2B  3072
#define P_G3   3200
#define P_N3B  3328
#define P_RPBSA 3456
#define P_RPBCA 4132

// wT (bf16 packed-fragment weights) offsets, elements
#define W_SAQ 0
#define W_SAK 16384
#define W_SAV 32768
#define W_SAP 49152
#define W_CAQ 65536
#define W_CAK 81920
#define W_CAV 98304
#define W_CAP 114688
#define W_W1T 131072
#define W_W2T 196608

struct Ptrs { const void* p[32]; };

__device__ __forceinline__ float bf2f(bf16 v) { return __bfloat162float(v); }
__device__ __forceinline__ bf16  f2bf(float v) { return __float2bfloat16(v); }
__device__ __forceinline__ short f2bs(float v) { bf16 t = __float2bfloat16(v); return *reinterpret_cast<short*>(&t); }
__device__ __forceinline__ float bs2f(short v) { bf16 t = *reinterpret_cast<bf16*>(&v); return __bfloat162float(t); }

__device__ __forceinline__ float ldi(const void* __restrict__ p, size_t i, int f) {
    return f ? ((const float*)p)[i] : bf2f(((const bf16*)p)[i]);
}

// token (wn, t) -> flat spatial row in (B, NC, H, W) layout (after roll by -SS)
__device__ __forceinline__ int tok_row(int wn, int t) {
    int b = wn >> 8, wrem = wn & 255, wi = wrem >> 4, wj = wrem & 15;
    int n = t / 49, p = t % 49, pi = p / 7, pj = p % 7;
    int i = (wi * 7 + pi + SSn) % Hn;
    int j = (wj * 7 + pj + SSn) % Wn;
    return ((b * NCn + n) * Hn + i) * Wn + j;
}

// Detect input dtype (bf16 exponent-band heuristic)
__global__ void k_detect(const unsigned int* __restrict__ xw, int* __restrict__ flag) {
    __shared__ int cnt;
    if (threadIdx.x == 0) cnt = 0;
    __syncthreads();
    int c = 0;
    for (int i = threadIdx.x; i < 8192; i += 256) {
        unsigned e = (xw[i] >> 7) & 0xffu;
        c += (e >= 100u && e <= 140u) ? 1 : 0;
    }
    atomicAdd(&cnt, c);
    __syncthreads();
    if (threadIdx.x == 0) *flag = (cnt < 4096) ? 1 : 0;   // 1 = fp32, 0 = bf16
}

__global__ __launch_bounds__(256) void k_copy(const void* __restrict__ x,
                                              const int* __restrict__ dflag,
                                              bf16* __restrict__ xr) {
    const int f = *dflag;
    size_t i8 = ((size_t)blockIdx.x * 256 + threadIdx.x) * 8;
    s16x8 v;
    if (f) {
        const float* s = (const float*)x + i8;
        #pragma unroll
        for (int j = 0; j < 8; ++j) v[j] = f2bs(s[j]);
    } else {
        v = *(const s16x8*)((const bf16*)x + i8);
    }
    *(s16x8*)(xr + i8) = v;
}

// All scalar parameter prep
__global__ __launch_bounds__(512) void k_params(Ptrs in, const int* __restrict__ dflag,
                                                float* __restrict__ P) {
    const int f = *dflag;
    int tid = threadIdx.x;
    if (tid < 384) {
        int n = tid >> 7, c = tid & 127;
        float aq = 0.f, ak = 0.f, aq2 = 0.f, ak2 = 0.f;
        for (int d = 0; d < Cn; ++d) {
            float ctv = ldi(in.p[2], n * Cn + d, f);
            float cev = ldi(in.p[3], n * Cn + d, f);
            aq  += ctv * ldi(in.p[10], d * Cn + c, f);
            ak  += ctv * ldi(in.p[12], d * Cn + c, f);
            aq2 += ctv * ldi(in.p[19], d * Cn + c, f);
            ak2 += cev * ldi(in.p[21], d * Cn + c, f);
        }
        P[P_QCSA + tid] = aq  + ldi(in.p[11], tid & 127, f);
        P[P_KCSA + tid] = ak  + ldi(in.p[13], tid & 127, f);
        P[P_QCCA + tid] = aq2 + ldi(in.p[20], tid & 127, f);
        P[P_KCCA + tid] = ak2 + ldi(in.p[22], tid & 127, f);
    }
    if (tid < 128) {
        P[P_VCSA + tid] = ldi(in.p[15], tid, f);
        P[P_BPSA + tid] = ldi(in.p[17], tid, f);
        P[P_VCCA + tid] = ldi(in.p[24], tid, f);
        P[P_BPCA + tid] = ldi(in.p[26], tid, f);
        P[P_B2   + tid] = ldi(in.p[31], tid, f);
        P[P_G1   + tid] = ldi(in.p[4],  tid, f);
        P[P_N1B  + tid] = ldi(in.p[5],  tid, f);
        P[P_G2   + tid] = ldi(in.p[6],  tid, f);
        P[P_N2B  + tid] = ldi(in.p[7],  tid, f);
        P[P_G3   + tid] = ldi(in.p[8],  tid, f);
        P[P_N3B  + tid] = ldi(in.p[9],  tid, f);
    }
    P[P_B1 + tid] = ldi(in.p[29], tid, f);
    for (int i = tid; i < 676; i += 512) {
        P[P_RPBSA + (i & 3) * 169 + (i >> 2)] = ldi(in.p[18], i, f);
        P[P_RPBCA + (i & 3) * 169 + (i >> 2)] = ldi(in.p[27], i, f);
    }
}

// Pack 8 square 128x128 weights into MFMA-fragment order
__global__ __launch_bounds__(64) void k_tsq(Ptrs in, const int* __restrict__ dflag,
                                            bf16* __restrict__ wT) {
    const int f = *dflag;
    const int map[8] = {10, 12, 14, 16, 19, 21, 23, 25};
    int mat = blockIdx.y, ntks = blockIdx.x, lane = threadIdx.x;
    int ntile = ntks >> 2, ks = ntks & 3;
    int n = ntile * 16 + (lane & 15), k0 = ks * 32 + (lane >> 4) * 8;
    const void* src = in.p[map[mat]];
    s16x8 v;
    #pragma unroll
    for (int j = 0; j < 8; ++j) v[j] = f2bs(ldi(src, (size_t)(k0 + j) * 128 + n, f));
    *(s16x8*)(wT + mat * 16384 + ((size_t)ntks * 64 + lane) * 8) = v;
}

__global__ __launch_bounds__(64) void k_tmlp(Ptrs in, const int* __restrict__ dflag,
                                             bf16* __restrict__ wT) {
    const int f = *dflag;
    int bid = blockIdx.x, lane = threadIdx.x;
    s16x8 v;
    if (bid < 128) {
        int ntile = bid >> 2, ks = bid & 3;
        int n = ntile * 16 + (lane & 15), k0 = ks * 32 + (lane >> 4) * 8;
        #pragma unroll
        for (int j = 0; j < 8; ++j) v[j] = f2bs(ldi(in.p[28], (size_t)(k0 + j) * 512 + n, f));
        *(s16x8*)(wT + W_W1T + ((size_t)bid * 64 + lane) * 8) = v;
    } else {
        int b2 = bid - 128;
        int ntile = b2 >> 4, ks = b2 & 15;
        int n = ntile * 16 + (lane & 15), k0 = ks * 32 + (lane >> 4) * 8;
        #pragma unroll
        for (int j = 0; j < 8; ++j) v[j] = f2bs(ldi(in.p[30], (size_t)(k0 + j) * 128 + n, f));
        *(s16x8*)(wT + W_W2T + ((size_t)b2 * 64 + lane) * 8) = v;
    }
}

// Parallel in-LDS LN of row at rp (128 bf16), gamma/beta staged in LDS gb[0..255]
__device__ __forceinline__ void ln_inplace(char* __restrict__ rp, const float* __restrict__ gb) {
    float s = 0.f, s2 = 0.f;
    #pragma unroll
    for (int c8 = 0; c8 < 16; ++c8) {
        s16x8 v = *(const s16x8*)(rp + c8 * 16);
        #pragma unroll
        for (int j = 0; j < 8; ++j) { float fv = bs2f(v[j]); s += fv; s2 += fv * fv; }
    }
    float mean = s * (1.f / 128.f);
    float rstd = rsqrtf(s2 * (1.f / 128.f) - mean * mean + 1e-5f);
    #pragma unroll
    for (int c8 = 0; c8 < 16; ++c8) {
        s16x8 v = *(const s16x8*)(rp + c8 * 16);
        #pragma unroll
        for (int j = 0; j < 8; ++j) {
            int col = c8 * 8 + j;
            v[j] = f2bs((bs2f(v[j]) - mean) * rstd * gb[col] + gb[128 + col]);
        }
        *(s16x8*)(rp + c8 * 16) = v;
    }
}

// SA: bulk gather -> in-LDS LN1 -> Q/K/V GEMM (swapped MFMA, packed 8B stores)
__global__ __launch_bounds__(256) void k_qkv_sa(
    const bf16* __restrict__ xr, const float* __restrict__ P, const bf16* __restrict__ wT,
    bf16* __restrict__ tokQ, bf16* __restrict__ tokK, bf16* __restrict__ tokV) {
    __shared__ char ldsA[160 * SA];
    __shared__ int rowIdx[Tt];
    __shared__ float gb[256];
    int wn = blockIdx.x, tid = threadIdx.x;
    if (tid < Tt) rowIdx[tid] = tok_row(wn, tid);
    gb[tid] = tid < 128 ? P[P_G1 + tid] : P[P_N1B + tid - 128];
    for (int i = tid; i < 13 * SA / 4; i += 256) ((int*)(ldsA + 147 * SA))[i] = 0;
    __syncthreads();
    for (int idx = tid; idx < Tt * 16; idx += 256) {
        int t = idx >> 4, c8 = idx & 15;
        s16x8 v = *(const s16x8*)(xr + (size_t)rowIdx[t] * Cn + c8 * 8);
        *(s16x8*)(ldsA + t * SA + c8 * 16) = v;
    }
    __syncthreads();
    if (tid < Tt) ln_inplace(ldsA + tid * SA, gb);
    __syncthreads();
    int wv = tid >> 6, lane = tid & 63, l15 = lane & 15, lg = lane >> 4;
    #pragma unroll 1
    for (int mat = 0; mat < 3; ++mat) {
        const bf16* W = wT + mat * 16384;
        bf16* dst = mat == 0 ? tokQ : (mat == 1 ? tokK : tokV);
        #pragma unroll 1
        for (int ni = 0; ni < 2; ++ni) {
            int nt = wv * 2 + ni;
            f32x4 acc[10] = {};
            #pragma unroll
            for (int ks = 0; ks < 4; ++ks) {
                s16x8 bfrag = *(const s16x8*)(W + (((nt << 2) + ks) * 64 + lane) * 8);
                #pragma unroll
                for (int mt = 0; mt < 10; ++mt) {
                    s16x8 af = *(const s16x8*)(ldsA + (mt * 16 + l15) * SA + ks * 64 + lg * 16);
                    acc[mt] = MFMA(bfrag, af, acc[mt]);   // swapped: D[wcol][token]
                }
            }
            int col0 = nt * 16 + lg * 4;
            #pragma unroll
            for (int mt = 0; mt < 10; ++mt) {
                int t = mt * 16 + l15;
                if (t < Tt) {
                    int n = t / 49;
                    s16x4 pk;
                    if (mat == 0) {
                        f32x4 b4 = *(const f32x4*)(P + P_QCSA + n * 128 + col0);
                        #pragma unroll
                        for (int r = 0; r < 4; ++r) pk[r] = f2bs((acc[mt][r] + b4[r]) * SCALE);
                    } else if (mat == 1) {
                        f32x4 b4 = *(const f32x4*)(P + P_KCSA + n * 128 + col0);
                        #pragma unroll
                        for (int r = 0; r < 4; ++r) pk[r] = f2bs(acc[mt][r] + b4[r]);
                    } else {
                        f32x4 b4 = *(const f32x4*)(P + P_VCSA + col0);
                        #pragma unroll
                        for (int r = 0; r < 4; ++r) pk[r] = f2bs(acc[mt][r] + b4[r]);
                    }
                    *(s16x4*)(dst + ((size_t)wn * Tt + t) * Cn + col0) = pk;
                }
            }
        }
    }
}

// CA: Q from in-LDS LN2; K/V from gathered x_kv (dual dtype)
__global__ __launch_bounds__(256) void k_qkv_ca(
    const bf16* __restrict__ xr, const void* __restrict__ xkv,
    const float* __restrict__ P, const bf16* __restrict__ wT,
    const int* __restrict__ dflag,
    bf16* __restrict__ tokQ, bf16* __restrict__ tokK, bf16* __restrict__ tokV) {
    const int f = *dflag;
    __shared__ char ldsA[160 * SA];
    __shared__ int rowIdx[Tt];
    __shared__ float gb[256];
    int wn = blockIdx.x, tid = threadIdx.x;
    if (tid < Tt) rowIdx[tid] = tok_row(wn, tid);
    gb[tid] = tid < 128 ? P[P_G2 + tid] : P[P_N2B + tid - 128];
    for (int i = tid; i < 13 * SA / 4; i += 256) ((int*)(ldsA + 147 * SA))[i] = 0;
    __syncthreads();
    for (int idx = tid; idx < Tt * 16; idx += 256) {
        int t = idx >> 4, c8 = idx & 15;
        s16x8 v = *(const s16x8*)(xr + (size_t)rowIdx[t] * Cn + c8 * 8);
        *(s16x8*)(ldsA + t * SA + c8 * 16) = v;
    }
    __syncthreads();
    if (tid < Tt) ln_inplace(ldsA + tid * SA, gb);
    __syncthreads();
    int wv = tid >> 6, lane = tid & 63, l15 = lane & 15, lg = lane >> 4;
    // Q projection
    {
        const bf16* W = wT + W_CAQ;
        #pragma unroll 1
        for (int ni = 0; ni < 2; ++ni) {
            int nt = wv * 2 + ni;
            f32x4 acc[10] = {};
            #pragma unroll
            for (int ks = 0; ks < 4; ++ks) {
                s16x8 bfrag = *(const s16x8*)(W + (((nt << 2) + ks) * 64 + lane) * 8);
                #pragma unroll
                for (int mt = 0; mt < 10; ++mt) {
                    s16x8 af = *(const s16x8*)(ldsA + (mt * 16 + l15) * SA + ks * 64 + lg * 16);
                    acc[mt] = MFMA(bfrag, af, acc[mt]);
                }
            }
            int col0 = nt * 16 + lg * 4;
            #pragma unroll
            for (int mt = 0; mt < 10; ++mt) {
                int t = mt * 16 + l15;
                if (t < Tt) {
                    int n = t / 49;
                    f32x4 b4 = *(const f32x4*)(P + P_QCCA + n * 128 + col0);
                    s16x4 pk;
                    #pragma unroll
                    for (int r = 0; r < 4; ++r) pk[r] = f2bs((acc[mt][r] + b4[r]) * SCALE);
                    *(s16x4*)(tokQ + ((size_t)wn * Tt + t) * Cn + col0) = pk;
                }
            }
        }
    }
    __syncthreads();
    for (int idx = tid; idx < Tt * 16; idx += 256) {
        int t = idx >> 4, c8 = idx & 15;
        s16x8 v;
        if (f) {
            const float* s = (const float*)xkv + (size_t)rowIdx[t] * Cn + c8 * 8;
            #pragma unroll
            for (int j = 0; j < 8; ++j) v[j] = f2bs(s[j]);
        } else {
            v = *(const s16x8*)((const bf16*)xkv + (size_t)rowIdx[t] * Cn + c8 * 8);
        }
        *(s16x8*)(ldsA + t * SA + c8 * 16) = v;
    }
    __syncthreads();
    #pragma unroll 1
    for (int mat = 0; mat < 2; ++mat) {
        const bf16* W = wT + (mat == 0 ? W_CAK : W_CAV);
        bf16* dst = mat == 0 ? tokK : tokV;
        #pragma unroll 1
        for (int ni = 0; ni < 2; ++ni) {
            int nt = wv * 2 + ni;
            f32x4 acc[10] = {};
            #pragma unroll
            for (int ks = 0; ks < 4; ++ks) {
                s16x8 bfrag = *(const s16x8*)(W + (((nt << 2) + ks) * 64 + lane) * 8);
                #pragma unroll
                for (int mt = 0; mt < 10; ++mt) {
                    s16x8 af = *(const s16x8*)(ldsA + (mt * 16 + l15) * SA + ks * 64 + lg * 16);
                    acc[mt] = MFMA(bfrag, af, acc[mt]);
                }
            }
            int col0 = nt * 16 + lg * 4;
            #pragma unroll
            for (int mt = 0; mt < 10; ++mt) {
                int t = mt * 16 + l15;
                if (t < Tt) {
                    int n = t / 49;
                    f32x4 b4 = (mat == 0) ? *(const f32x4*)(P + P_KCCA + n * 128 + col0)
                                          : *(const f32x4*)(P + P_VCCA + col0);
                    s16x4 pk;
                    #pragma unroll
                    for (int r = 0; r < 4; ++r) pk[r] = f2bs(acc[mt][r] + b4[r]);
                    *(s16x4*)(dst + ((size_t)wn * Tt + t) * Cn + col0) = pk;
                }
            }
        }
    }
}

// MFMA attention: swapped PV -> packed 8B O-stores
__global__ __launch_bounds__(256) void k_attn(
    const bf16* __restrict__ Q, const bf16* __restrict__ K, const bf16* __restrict__ V,
    bf16* __restrict__ O, const float* __restrict__ rpbf) {
    __shared__ char ldsK[40 * 256];
    __shared__ char ldsV[32 * 336];
    __shared__ char ldsP[4 * 16 * 336];
    __shared__ float BM[49 * 52];
    __shared__ float lArr[4][16];
    int wn = blockIdx.x, h = blockIdx.y, tid = threadIdx.x;
    int wi = (wn >> 4) & 15, wj = wn & 15;
    size_t base = (size_t)wn * Tt * Cn + h * HDn;
    for (int idx = tid; idx < 640; idx += 256) {
        int key = idx >> 2, ch = idx & 3;
        s16x8 kv = {}, vv = {};
        if (key < Tt) {
            kv = *(const s16x8*)(K + base + (size_t)key * Cn + ch * 8);
            vv = *(const s16x8*)(V + base + (size_t)key * Cn + ch * 8);
        }
        *(s16x8*)(ldsK + (key >> 2) * 256 + (key & 3) * 64 + ch * 16) = kv;
        #pragma unroll
        for (int j = 0; j < 8; ++j)
            *(short*)(ldsV + (ch * 8 + j) * 336 + key * 2) = vv[j];
    }
    for (int idx = tid; idx < 2401; idx += 256) {
        int qp = idx / 49, kp = idx - qp * 49;
        int qpi = qp / 7, qpj = qp - qpi * 7, kpi = kp / 7, kpj = kp - kpi * 7;
        float bias = rpbf[h * 169 + (qpi - kpi + 6) * 13 + (qpj - kpj + 6)];
        int qi = wi * 7 + qpi, qj = wj * 7 + qpj, ki = wi * 7 + kpi, kj = wj * 7 + kpj;
        int rq = (qi < 105 ? 0 : (qi < 109 ? 1 : 2)) * 3 + (qj < 105 ? 0 : (qj < 109 ? 1 : 2));
        int rk = (ki < 105 ? 0 : (ki < 109 ? 1 : 2)) * 3 + (kj < 105 ? 0 : (kj < 109 ? 1 : 2));
        BM[qp * 52 + kp] = bias + (rq == rk ? 0.f : -100.f);
    }
    __syncthreads();
    int wv = tid >> 6, lane = tid & 63, l15 = lane & 15, lg = lane >> 4;
    char* myP = ldsP + wv * (16 * 336);
    for (int mt = wv; mt < 10; mt += 4) {
        int qrow = mt * 16 + l15; if (qrow > 146) qrow = 146;
        s16x8 qf = *(const s16x8*)(Q + base + (size_t)qrow * Cn + lg * 8);
        f32x4 acc[10];
        #pragma unroll
        for (int nt = 0; nt < 10; ++nt) {
            int key = nt * 16 + l15;
            s16x8 bfrag = *(const s16x8*)(ldsK + (key >> 2) * 256 + (key & 3) * 64 + lg * 16);
            f32x4 z = {};
            acc[nt] = MFMA(qf, bfrag, z);
        }
        float linv[4];
        #pragma unroll
        for (int r = 0; r < 4; ++r) {
            int row = mt * 16 + lg * 4 + r;
            int qp = row - (row >= 147 ? 147 : (row >= 98 ? 98 : (row >= 49 ? 49 : 0)));
            float s[10], m = -1e30f;
            #pragma unroll
            for (int nt = 0; nt < 10; ++nt) {
                int key = nt * 16 + l15;
                int kp = key - (key >= 147 ? 147 : (key >= 98 ? 98 : (key >= 49 ? 49 : 0)));
                float sv = acc[nt][r] + BM[qp * 52 + kp];
                if (nt == 9 && l15 >= 3) sv = -1e30f;
                s[nt] = sv;
                m = fmaxf(m, sv);
            }
            #pragma unroll
            for (int off = 1; off < 16; off <<= 1) m = fmaxf(m, __shfl_xor(m, off));
            float l = 0.f;
            #pragma unroll
            for (int nt = 0; nt < 10; ++nt) {
                float p = (nt == 9 && l15 >= 3) ? 0.f : __expf(s[nt] - m);
                l += p;
                *(bf16*)(myP + (lg * 4 + r) * 336 + (nt * 16 + l15) * 2) = f2bf(p);
            }
            #pragma unroll
            for (int off = 1; off < 16; off <<= 1) l += __shfl_xor(l, off);
            linv[r] = 1.f / l;
        }
        // transpose 1/l across the 16-lane group via LDS (q = l15 after PV swap)
        if (l15 == 0) {
            #pragma unroll
            for (int r = 0; r < 4; ++r) lArr[wv][lg * 4 + r] = linv[r];
        }
        float myinv = lArr[wv][l15];
        #pragma unroll
        for (int ntv = 0; ntv < 2; ++ntv) {
            f32x4 ao = {};
            #pragma unroll
            for (int ks = 0; ks < 5; ++ks) {
                s16x8 af = *(const s16x8*)(myP + l15 * 336 + ks * 64 + lg * 16);
                s16x8 vf = *(const s16x8*)(ldsV + (ntv * 16 + l15) * 336 + ks * 64 + lg * 16);
                ao = MFMA(vf, af, ao);   // swapped: D[dcol][q]
            }
            int q = mt * 16 + l15;
            if (q < Tt) {
                s16x4 pk;
                #pragma unroll
                for (int r = 0; r < 4; ++r) pk[r] = f2bs(ao[r] * myinv);
                *(s16x4*)(O + base + (size_t)q * Cn + ntv * 16 + lg * 4) = pk;
            }
        }
    }
}

// Output projection (swapped MFMA) + packed 8B residual RMW into xr
__global__ __launch_bounds__(256) void k_proj(
    const bf16* __restrict__ tokO, const float* __restrict__ P, const bf16* __restrict__ W,
    int bpOff, bf16* __restrict__ xr) {
    __shared__ char ldsA[160 * SA];
    __shared__ int rowIdx[Tt];
    int wn = blockIdx.x, tid = threadIdx.x;
    if (tid < Tt) rowIdx[tid] = tok_row(wn, tid);
    for (int i = tid; i < 13 * SA / 4; i += 256) ((int*)(ldsA + 147 * SA))[i] = 0;
    __syncthreads();
    for (int idx = tid; idx < Tt * 16; idx += 256) {
        int t = idx >> 4, c8 = idx & 15;
        s16x8 v = *(const s16x8*)(tokO + ((size_t)wn * Tt + t) * Cn + c8 * 8);
        *(s16x8*)(ldsA + t * SA + c8 * 16) = v;
    }
    __syncthreads();
    int wv = tid >> 6, lane = tid & 63, l15 = lane & 15, lg = lane >> 4;
    #pragma unroll 1
    for (int ni = 0; ni < 2; ++ni) {
        int nt = wv * 2 + ni;
        f32x4 acc[10] = {};
        #pragma unroll
        for (int ks = 0; ks < 4; ++ks) {
            s16x8 bfrag = *(const s16x8*)(W + (((nt << 2) + ks) * 64 + lane) * 8);
            #pragma unroll
            for (int mt = 0; mt < 10; ++mt) {
                s16x8 af = *(const s16x8*)(ldsA + (mt * 16 + l15) * SA + ks * 64 + lg * 16);
                acc[mt] = MFMA(bfrag, af, acc[mt]);
            }
        }
        int col0 = nt * 16 + lg * 4;
        f32x4 bp4 = *(const f32x4*)(P + bpOff + col0);
        #pragma unroll
        for (int mt = 0; mt < 10; ++mt) {
            int t = mt * 16 + l15;
            if (t < Tt) {
                size_t o = (size_t)rowIdx[t] * Cn + col0;
                s16x4 cur = *(const s16x4*)(xr + o);
                s16x4 pk;
                #pragma unroll
                for (int r = 0; r < 4; ++r) pk[r] = f2bs(bs2f(cur[r]) + acc[mt][r] + bp4[r]);
                *(s16x4*)(xr + o) = pk;
            }
        }
    }
}

// Fused LN3 + MLP (swapped MFMA, packed stores)
__global__ __launch_bounds__(256) void k_mlp(
    const bf16* __restrict__ xr, const float* __restrict__ P, const bf16* __restrict__ wT,
    const int* __restrict__ dflag, void* __restrict__ outp) {
    __shared__ char ldsA[32 * SA];
    __shared__ char ldsH[32 * SH];
    __shared__ float gb[256];
    int tid = threadIdx.x;
    size_t t0 = (size_t)blockIdx.x * 32;
    gb[tid] = tid < 128 ? P[P_G3 + tid] : P[P_N3B + tid - 128];
    __syncthreads();
    for (int idx = tid; idx < 32 * 16; idx += 256) {
        int t = idx >> 4, c8 = idx & 15;
        s16x8 v = *(const s16x8*)(xr + (t0 + t) * Cn + c8 * 8);
        *(s16x8*)(ldsA + t * SA + c8 * 16) = v;
    }
    __syncthreads();
    if (tid < 32) ln_inplace(ldsA + tid * SA, gb);
    __syncthreads();
    int wv = tid >> 6, lane = tid & 63, l15 = lane & 15, lg = lane >> 4;
    const bf16* W1 = wT + W_W1T;
    {
        // token fragments (2 m-tiles x 4 ks) hoisted to registers
        s16x8 a0[4], a1[4];
        #pragma unroll
        for (int ks = 0; ks < 4; ++ks) {
            a0[ks] = *(const s16x8*)(ldsA + l15 * SA + ks * 64 + lg * 16);
            a1[ks] = *(const s16x8*)(ldsA + (16 + l15) * SA + ks * 64 + lg * 16);
        }
        #pragma unroll 1
        for (int ni = 0; ni < 8; ++ni) {
            int nt = wv * 8 + ni;
            f32x4 acc0 = {}, acc1 = {};
            #pragma unroll
            for (int ks = 0; ks < 4; ++ks) {
                s16x8 bfrag = *(const s16x8*)(W1 + (((nt << 2) + ks) * 64 + lane) * 8);
                acc0 = MFMA(bfrag, a0[ks], acc0);
                acc1 = MFMA(bfrag, a1[ks], acc1);
            }
            int col0 = nt * 16 + lg * 4;
            f32x4 b14 = *(const f32x4*)(P + P_B1 + col0);
            s16x4 p0, p1;
            #pragma unroll
            for (int r = 0; r < 4; ++r) {
                float v0 = acc0[r] + b14[r];
                p0[r] = f2bs(0.5f * v0 * (1.f + erff(v0 * 0.70710678118654752f)));
                float v1 = acc1[r] + b14[r];
                p1[r] = f2bs(0.5f * v1 * (1.f + erff(v1 * 0.70710678118654752f)));
            }
            *(s16x4*)(ldsH + l15 * SH + col0 * 2) = p0;
            *(s16x4*)(ldsH + (16 + l15) * SH + col0 * 2) = p1;
        }
    }
    __syncthreads();
    const int f = *dflag;
    const bf16* W2 = wT + W_W2T;
    #pragma unroll 1
    for (int ni = 0; ni < 2; ++ni) {
        int nt = wv * 2 + ni;
        f32x4 acc0 = {}, acc1 = {};
        #pragma unroll
        for (int ks = 0; ks < 16; ++ks) {
            s16x8 bfrag = *(const s16x8*)(W2 + (((nt << 4) + ks) * 64 + lane) * 8);
            s16x8 af0 = *(const s16x8*)(ldsH + l15 * SH + ks * 64 + lg * 16);
            s16x8 af1 = *(const s16x8*)(ldsH + (16 + l15) * SH + ks * 64 + lg * 16);
            acc0 = MFMA(bfrag, af0, acc0);
            acc1 = MFMA(bfrag, af1, acc1);
        }
        int col0 = nt * 16 + lg * 4;
        f32x4 b24 = *(const f32x4*)(P + P_B2 + col0);
        size_t g0 = (t0 + l15) * Cn + col0;
        size_t g1 = (t0 + 16 + l15) * Cn + col0;
        s16x4 c0 = *(const s16x4*)(xr + g0);
        s16x4 c1 = *(const s16x4*)(xr + g1);
        if (f) {
            f32x4 o0, o1;
            #pragma unroll
            for (int r = 0; r < 4; ++r) {
                o0[r] = bs2f(c0[r]) + acc0[r] + b24[r];
                o1[r] = bs2f(c1[r]) + acc1[r] + b24[r];
            }
            *(f32x4*)((float*)outp + g0) = o0;
            *(f32x4*)((float*)outp + g1) = o1;
        } else {
            s16x4 p0, p1;
            #pragma unroll
            for (int r = 0; r < 4; ++r) {
                p0[r] = f2bs(bs2f(c0[r]) + acc0[r] + b24[r]);
                p1[r] = f2bs(bs2f(c1[r]) + acc1[r] + b24[r]);
            }
            *(s16x4*)((bf16*)outp + g0) = p0;
            *(s16x4*)((bf16*)outp + g1) = p1;
        }
    }
}

extern "C" void kernel_launch(void* const* d_in, const int* in_sizes, int n_in,
                              void* d_out, int out_size, void* d_ws, size_t ws_size,
                              hipStream_t stream) {
    Ptrs ptrs;
    for (int i = 0; i < 32; ++i) ptrs.p[i] = d_in[i];

    char* base = (char*)d_ws;
    float* P    = (float*)base;                   // 8192 f32 = 32 KB
    int*  dflag = (int*)(base + 32768);
    bf16* wT    = (bf16*)(base + 33024);          // 262144 bf16 = 512 KB
    bf16* xr    = wT + 262144;                    // NE bf16 residual
    bf16* tokK  = xr + NE;
    bf16* tokV  = tokK + NE;
    bf16* tokQ  = (bf16*)d_out;                   // Q and O alias in d_out

    k_detect<<<1, 256, 0, stream>>>((const unsigned int*)d_in[0], dflag);
    k_copy<<<(int)(NE / 2048), 256, 0, stream>>>(d_in[0], dflag, xr);
    k_params<<<1, 512, 0, stream>>>(ptrs, dflag, P);
    k_tsq<<<dim3(32, 8), 64, 0, stream>>>(ptrs, dflag, wT);
    k_tmlp<<<256, 64, 0, stream>>>(ptrs, dflag, wT);
    // ---- self-attention stage ----
    k_qkv_sa<<<WNt, 256, 0, stream>>>(xr, P, wT, tokQ, tokK, tokV);
    k_attn<<<dim3(WNt, HEADS), 256, 0, stream>>>(tokQ, tokK, tokV, tokQ, P + P_RPBSA);
    k_proj<<<WNt, 256, 0, stream>>>(tokQ, P, wT + W_SAP, P_BPSA, xr);
    // ---- cross-attention stage ----
    k_qkv_ca<<<WNt, 256, 0, stream>>>(xr, d_in[1], P, wT, dflag, tokQ, tokK, tokV);
    k_attn<<<dim3(WNt, HEADS), 256, 0, stream>>>(tokQ, tokK, tokV, tokQ, P + P_RPBCA);
    k_proj<<<WNt, 256, 0, stream>>>(tokQ, P, wT + W_CAP, P_BPCA, xr);
    // ---- MLP stage ----
    k_mlp<<<(int)(NE / Cn / 32), 256, 0, stream>>>(xr, P, wT, dflag, d_out);
}

// Round 7
// 705.512 us; speedup vs baseline: 11.8483x; 1.0503x over previous
//
#include <hip/hip_runtime.h>
#include <hip/hip_bf16.h>

typedef __hip_bfloat16 bf16;

#define Bn    4
#define NCn   3
#define Hn    112
#define Wn    112
#define Cn    128
#define HEADS 4
#define WSn   7
#define SSn   3
#define HDn   32
#define WNt   1024            // total windows = B * 16 * 16
#define Tt    147             // tokens per window = NC * 49
#define SCALE 0.17677669529663687f

// LDS strides: row-stride ≡ 8 dwords mod 32 -> 16 distinct bank starts (4-way max)
#define SA    288
#define SH    1056
#define MT    48              // k_mlp token tile

static const size_t NE = (size_t)Bn * NCn * Hn * Wn * Cn; // 19,267,584

typedef float f32x4 __attribute__((ext_vector_type(4)));
typedef short s16x8 __attribute__((ext_vector_type(8)));
typedef short s16x4 __attribute__((ext_vector_type(4)));
#define MFMA(a,b,c) __builtin_amdgcn_mfma_f32_16x16x32_bf16((a),(b),(c),0,0,0)

// P (f32 param block) offsets
#define P_QCSA 0
#define P_KCSA 384
#define P_QCCA 768
#define P_KCCA 1152
#define P_VCSA 1536
#define P_BPSA 1664
#define P_VCCA 1792
#define P_BPCA 1920
#define P_B1   2048
#define P_B2   2560
#define P_G1   2688
#define P_N1B  2816
#define P_G2   2944
#define P_N2B  3072
#define P_G3   3200
#define P_N3B  3328
#define P_RPBSA 3456
#define P_RPBCA 4132

// wT (bf16 packed-fragment weights) offsets, elements
#define W_SAQ 0
#define W_SAK 16384
#define W_SAV 32768
#define W_SAP 49152
#define W_CAQ 65536
#define W_CAK 81920
#define W_CAV 98304
#define W_CAP 114688
#define W_W1T 131072
#define W_W2T 196608

struct Ptrs { const void* p[32]; };

__device__ __forceinline__ float bf2f(bf16 v) { return __bfloat162float(v); }
__device__ __forceinline__ bf16  f2bf(float v) { return __float2bfloat16(v); }
__device__ __forceinline__ short f2bs(float v) { bf16 t = __float2bfloat16(v); return *reinterpret_cast<short*>(&t); }
__device__ __forceinline__ float bs2f(short v) { bf16 t = *reinterpret_cast<bf16*>(&v); return __bfloat162float(t); }

__device__ __forceinline__ float ldi(const void* __restrict__ p, size_t i, int f) {
    return f ? ((const float*)p)[i] : bf2f(((const bf16*)p)[i]);
}

// exact-enough GELU: tanh form, tanh via exp (max |diff vs erf-GELU| ~3e-3 in h1,
// -> <2e-3 at block output after w2; bf16 h1 rounding is already ~4e-3 relative)
__device__ __forceinline__ float gelu(float x) {
    float x2 = x * x;
    float u = x * (0.7978845608f + 0.0356774081f * x2);
    float t = 1.f - 2.f / (1.f + __expf(2.f * u));
    return 0.5f * x * (1.f + t);
}

// token (wn, t) -> flat spatial row in (B, NC, H, W) layout (after roll by -SS)
__device__ __forceinline__ int tok_row(int wn, int t) {
    int b = wn >> 8, wrem = wn & 255, wi = wrem >> 4, wj = wrem & 15;
    int n = t / 49, p = t % 49, pi = p / 7, pj = p % 7;
    int i = (wi * 7 + pi + SSn) % Hn;
    int j = (wj * 7 + pj + SSn) % Wn;
    return ((b * NCn + n) * Hn + i) * Wn + j;
}

// Detect input dtype (bf16 exponent-band heuristic)
__global__ void k_detect(const unsigned int* __restrict__ xw, int* __restrict__ flag) {
    __shared__ int cnt;
    if (threadIdx.x == 0) cnt = 0;
    __syncthreads();
    int c = 0;
    for (int i = threadIdx.x; i < 8192; i += 256) {
        unsigned e = (xw[i] >> 7) & 0xffu;
        c += (e >= 100u && e <= 140u) ? 1 : 0;
    }
    atomicAdd(&cnt, c);
    __syncthreads();
    if (threadIdx.x == 0) *flag = (cnt < 4096) ? 1 : 0;   // 1 = fp32, 0 = bf16
}

__global__ __launch_bounds__(256) void k_copy(const void* __restrict__ x,
                                              const int* __restrict__ dflag,
                                              bf16* __restrict__ xr) {
    const int f = *dflag;
    size_t i8 = ((size_t)blockIdx.x * 256 + threadIdx.x) * 8;
    s16x8 v;
    if (f) {
        const float* s = (const float*)x + i8;
        #pragma unroll
        for (int j = 0; j < 8; ++j) v[j] = f2bs(s[j]);
    } else {
        v = *(const s16x8*)((const bf16*)x + i8);
    }
    *(s16x8*)(xr + i8) = v;
}

// All scalar parameter prep
__global__ __launch_bounds__(512) void k_params(Ptrs in, const int* __restrict__ dflag,
                                                float* __restrict__ P) {
    const int f = *dflag;
    int tid = threadIdx.x;
    if (tid < 384) {
        int n = tid >> 7, c = tid & 127;
        float aq = 0.f, ak = 0.f, aq2 = 0.f, ak2 = 0.f;
        for (int d = 0; d < Cn; ++d) {
            float ctv = ldi(in.p[2], n * Cn + d, f);
            float cev = ldi(in.p[3], n * Cn + d, f);
            aq  += ctv * ldi(in.p[10], d * Cn + c, f);
            ak  += ctv * ldi(in.p[12], d * Cn + c, f);
            aq2 += ctv * ldi(in.p[19], d * Cn + c, f);
            ak2 += cev * ldi(in.p[21], d * Cn + c, f);
        }
        P[P_QCSA + tid] = aq  + ldi(in.p[11], tid & 127, f);
        P[P_KCSA + tid] = ak  + ldi(in.p[13], tid & 127, f);
        P[P_QCCA + tid] = aq2 + ldi(in.p[20], tid & 127, f);
        P[P_KCCA + tid] = ak2 + ldi(in.p[22], tid & 127, f);
    }
    if (tid < 128) {
        P[P_VCSA + tid] = ldi(in.p[15], tid, f);
        P[P_BPSA + tid] = ldi(in.p[17], tid, f);
        P[P_VCCA + tid] = ldi(in.p[24], tid, f);
        P[P_BPCA + tid] = ldi(in.p[26], tid, f);
        P[P_B2   + tid] = ldi(in.p[31], tid, f);
        P[P_G1   + tid] = ldi(in.p[4],  tid, f);
        P[P_N1B  + tid] = ldi(in.p[5],  tid, f);
        P[P_G2   + tid] = ldi(in.p[6],  tid, f);
        P[P_N2B  + tid] = ldi(in.p[7],  tid, f);
        P[P_G3   + tid] = ldi(in.p[8],  tid, f);
        P[P_N3B  + tid] = ldi(in.p[9],  tid, f);
    }
    P[P_B1 + tid] = ldi(in.p[29], tid, f);
    for (int i = tid; i < 676; i += 512) {
        P[P_RPBSA + (i & 3) * 169 + (i >> 2)] = ldi(in.p[18], i, f);
        P[P_RPBCA + (i & 3) * 169 + (i >> 2)] = ldi(in.p[27], i, f);
    }
}

// Pack 8 square 128x128 weights into MFMA-fragment order
__global__ __launch_bounds__(64) void k_tsq(Ptrs in, const int* __restrict__ dflag,
                                            bf16* __restrict__ wT) {
    const int f = *dflag;
    const int map[8] = {10, 12, 14, 16, 19, 21, 23, 25};
    int mat = blockIdx.y, ntks = blockIdx.x, lane = threadIdx.x;
    int ntile = ntks >> 2, ks = ntks & 3;
    int n = ntile * 16 + (lane & 15), k0 = ks * 32 + (lane >> 4) * 8;
    const void* src = in.p[map[mat]];
    s16x8 v;
    #pragma unroll
    for (int j = 0; j < 8; ++j) v[j] = f2bs(ldi(src, (size_t)(k0 + j) * 128 + n, f));
    *(s16x8*)(wT + mat * 16384 + ((size_t)ntks * 64 + lane) * 8) = v;
}

__global__ __launch_bounds__(64) void k_tmlp(Ptrs in, const int* __restrict__ dflag,
                                             bf16* __restrict__ wT) {
    const int f = *dflag;
    int bid = blockIdx.x, lane = threadIdx.x;
    s16x8 v;
    if (bid < 128) {
        int ntile = bid >> 2, ks = bid & 3;
        int n = ntile * 16 + (lane & 15), k0 = ks * 32 + (lane >> 4) * 8;
        #pragma unroll
        for (int j = 0; j < 8; ++j) v[j] = f2bs(ldi(in.p[28], (size_t)(k0 + j) * 512 + n, f));
        *(s16x8*)(wT + W_W1T + ((size_t)bid * 64 + lane) * 8) = v;
    } else {
        int b2 = bid - 128;
        int ntile = b2 >> 4, ks = b2 & 15;
        int n = ntile * 16 + (lane & 15), k0 = ks * 32 + (lane >> 4) * 8;
        #pragma unroll
        for (int j = 0; j < 8; ++j) v[j] = f2bs(ldi(in.p[30], (size_t)(k0 + j) * 128 + n, f));
        *(s16x8*)(wT + W_W2T + ((size_t)b2 * 64 + lane) * 8) = v;
    }
}

// Parallel in-LDS LN of row at rp (128 bf16), gamma/beta staged in LDS gb[0..255]
__device__ __forceinline__ void ln_inplace(char* __restrict__ rp, const float* __restrict__ gb) {
    float s = 0.f, s2 = 0.f;
    #pragma unroll
    for (int c8 = 0; c8 < 16; ++c8) {
        s16x8 v = *(const s16x8*)(rp + c8 * 16);
        #pragma unroll
        for (int j = 0; j < 8; ++j) { float fv = bs2f(v[j]); s += fv; s2 += fv * fv; }
    }
    float mean = s * (1.f / 128.f);
    float rstd = rsqrtf(s2 * (1.f / 128.f) - mean * mean + 1e-5f);
    #pragma unroll
    for (int c8 = 0; c8 < 16; ++c8) {
        s16x8 v = *(const s16x8*)(rp + c8 * 16);
        #pragma unroll
        for (int j = 0; j < 8; ++j) {
            int col = c8 * 8 + j;
            v[j] = f2bs((bs2f(v[j]) - mean) * rstd * gb[col] + gb[128 + col]);
        }
        *(s16x8*)(rp + c8 * 16) = v;
    }
}

// SA: bulk gather -> in-LDS LN1 -> Q/K/V GEMM (swapped MFMA, packed 8B stores)
__global__ __launch_bounds__(256) void k_qkv_sa(
    const bf16* __restrict__ xr, const float* __restrict__ P, const bf16* __restrict__ wT,
    bf16* __restrict__ tokQ, bf16* __restrict__ tokK, bf16* __restrict__ tokV) {
    __shared__ char ldsA[160 * SA];
    __shared__ int rowIdx[Tt];
    __shared__ float gb[256];
    int wn = blockIdx.x, tid = threadIdx.x;
    if (tid < Tt) rowIdx[tid] = tok_row(wn, tid);
    gb[tid] = tid < 128 ? P[P_G1 + tid] : P[P_N1B + tid - 128];
    for (int i = tid; i < 13 * SA / 4; i += 256) ((int*)(ldsA + 147 * SA))[i] = 0;
    __syncthreads();
    for (int idx = tid; idx < Tt * 16; idx += 256) {
        int t = idx >> 4, c8 = idx & 15;
        s16x8 v = *(const s16x8*)(xr + (size_t)rowIdx[t] * Cn + c8 * 8);
        *(s16x8*)(ldsA + t * SA + c8 * 16) = v;
    }
    __syncthreads();
    if (tid < Tt) ln_inplace(ldsA + tid * SA, gb);
    __syncthreads();
    int wv = tid >> 6, lane = tid & 63, l15 = lane & 15, lg = lane >> 4;
    #pragma unroll 1
    for (int mat = 0; mat < 3; ++mat) {
        const bf16* W = wT + mat * 16384;
        bf16* dst = mat == 0 ? tokQ : (mat == 1 ? tokK : tokV);
        #pragma unroll 1
        for (int ni = 0; ni < 2; ++ni) {
            int nt = wv * 2 + ni;
            f32x4 acc[10] = {};
            #pragma unroll
            for (int ks = 0; ks < 4; ++ks) {
                s16x8 bfrag = *(const s16x8*)(W + (((nt << 2) + ks) * 64 + lane) * 8);
                #pragma unroll
                for (int mt = 0; mt < 10; ++mt) {
                    s16x8 af = *(const s16x8*)(ldsA + (mt * 16 + l15) * SA + ks * 64 + lg * 16);
                    acc[mt] = MFMA(bfrag, af, acc[mt]);   // swapped: D[wcol][token]
                }
            }
            int col0 = nt * 16 + lg * 4;
            #pragma unroll
            for (int mt = 0; mt < 10; ++mt) {
                int t = mt * 16 + l15;
                if (t < Tt) {
                    int n = t / 49;
                    s16x4 pk;
                    if (mat == 0) {
                        f32x4 b4 = *(const f32x4*)(P + P_QCSA + n * 128 + col0);
                        #pragma unroll
                        for (int r = 0; r < 4; ++r) pk[r] = f2bs((acc[mt][r] + b4[r]) * SCALE);
                    } else if (mat == 1) {
                        f32x4 b4 = *(const f32x4*)(P + P_KCSA + n * 128 + col0);
                        #pragma unroll
                        for (int r = 0; r < 4; ++r) pk[r] = f2bs(acc[mt][r] + b4[r]);
                    } else {
                        f32x4 b4 = *(const f32x4*)(P + P_VCSA + col0);
                        #pragma unroll
                        for (int r = 0; r < 4; ++r) pk[r] = f2bs(acc[mt][r] + b4[r]);
                    }
                    *(s16x4*)(dst + ((size_t)wn * Tt + t) * Cn + col0) = pk;
                }
            }
        }
    }
}

// CA: Q from in-LDS LN2; K/V from gathered x_kv (dual dtype)
__global__ __launch_bounds__(256) void k_qkv_ca(
    const bf16* __restrict__ xr, const void* __restrict__ xkv,
    const float* __restrict__ P, const bf16* __restrict__ wT,
    const int* __restrict__ dflag,
    bf16* __restrict__ tokQ, bf16* __restrict__ tokK, bf16* __restrict__ tokV) {
    const int f = *dflag;
    __shared__ char ldsA[160 * SA];
    __shared__ int rowIdx[Tt];
    __shared__ float gb[256];
    int wn = blockIdx.x, tid = threadIdx.x;
    if (tid < Tt) rowIdx[tid] = tok_row(wn, tid);
    gb[tid] = tid < 128 ? P[P_G2 + tid] : P[P_N2B + tid - 128];
    for (int i = tid; i < 13 * SA / 4; i += 256) ((int*)(ldsA + 147 * SA))[i] = 0;
    __syncthreads();
    for (int idx = tid; idx < Tt * 16; idx += 256) {
        int t = idx >> 4, c8 = idx & 15;
        s16x8 v = *(const s16x8*)(xr + (size_t)rowIdx[t] * Cn + c8 * 8);
        *(s16x8*)(ldsA + t * SA + c8 * 16) = v;
    }
    __syncthreads();
    if (tid < Tt) ln_inplace(ldsA + tid * SA, gb);
    __syncthreads();
    int wv = tid >> 6, lane = tid & 63, l15 = lane & 15, lg = lane >> 4;
    // Q projection
    {
        const bf16* W = wT + W_CAQ;
        #pragma unroll 1
        for (int ni = 0; ni < 2; ++ni) {
            int nt = wv * 2 + ni;
            f32x4 acc[10] = {};
            #pragma unroll
            for (int ks = 0; ks < 4; ++ks) {
                s16x8 bfrag = *(const s16x8*)(W + (((nt << 2) + ks) * 64 + lane) * 8);
                #pragma unroll
                for (int mt = 0; mt < 10; ++mt) {
                    s16x8 af = *(const s16x8*)(ldsA + (mt * 16 + l15) * SA + ks * 64 + lg * 16);
                    acc[mt] = MFMA(bfrag, af, acc[mt]);
                }
            }
            int col0 = nt * 16 + lg * 4;
            #pragma unroll
            for (int mt = 0; mt < 10; ++mt) {
                int t = mt * 16 + l15;
                if (t < Tt) {
                    int n = t / 49;
                    f32x4 b4 = *(const f32x4*)(P + P_QCCA + n * 128 + col0);
                    s16x4 pk;
                    #pragma unroll
                    for (int r = 0; r < 4; ++r) pk[r] = f2bs((acc[mt][r] + b4[r]) * SCALE);
                    *(s16x4*)(tokQ + ((size_t)wn * Tt + t) * Cn + col0) = pk;
                }
            }
        }
    }
    __syncthreads();
    for (int idx = tid; idx < Tt * 16; idx += 256) {
        int t = idx >> 4, c8 = idx & 15;
        s16x8 v;
        if (f) {
            const float* s = (const float*)xkv + (size_t)rowIdx[t] * Cn + c8 * 8;
            #pragma unroll
            for (int j = 0; j < 8; ++j) v[j] = f2bs(s[j]);
        } else {
            v = *(const s16x8*)((const bf16*)xkv + (size_t)rowIdx[t] * Cn + c8 * 8);
        }
        *(s16x8*)(ldsA + t * SA + c8 * 16) = v;
    }
    __syncthreads();
    #pragma unroll 1
    for (int mat = 0; mat < 2; ++mat) {
        const bf16* W = wT + (mat == 0 ? W_CAK : W_CAV);
        bf16* dst = mat == 0 ? tokK : tokV;
        #pragma unroll 1
        for (int ni = 0; ni < 2; ++ni) {
            int nt = wv * 2 + ni;
            f32x4 acc[10] = {};
            #pragma unroll
            for (int ks = 0; ks < 4; ++ks) {
                s16x8 bfrag = *(const s16x8*)(W + (((nt << 2) + ks) * 64 + lane) * 8);
                #pragma unroll
                for (int mt = 0; mt < 10; ++mt) {
                    s16x8 af = *(const s16x8*)(ldsA + (mt * 16 + l15) * SA + ks * 64 + lg * 16);
                    acc[mt] = MFMA(bfrag, af, acc[mt]);
                }
            }
            int col0 = nt * 16 + lg * 4;
            #pragma unroll
            for (int mt = 0; mt < 10; ++mt) {
                int t = mt * 16 + l15;
                if (t < Tt) {
                    int n = t / 49;
                    f32x4 b4 = (mat == 0) ? *(const f32x4*)(P + P_KCCA + n * 128 + col0)
                                          : *(const f32x4*)(P + P_VCCA + col0);
                    s16x4 pk;
                    #pragma unroll
                    for (int r = 0; r < 4; ++r) pk[r] = f2bs(acc[mt][r] + b4[r]);
                    *(s16x4*)(dst + ((size_t)wn * Tt + t) * Cn + col0) = pk;
                }
            }
        }
    }
}

// MFMA attention: swapped PV -> packed 8B O-stores
__global__ __launch_bounds__(256) void k_attn(
    const bf16* __restrict__ Q, const bf16* __restrict__ K, const bf16* __restrict__ V,
    bf16* __restrict__ O, const float* __restrict__ rpbf) {
    __shared__ char ldsK[40 * 256];
    __shared__ char ldsV[32 * 336];
    __shared__ char ldsP[4 * 16 * 336];
    __shared__ float BM[49 * 52];
    __shared__ float lArr[4][16];
    int wn = blockIdx.x, h = blockIdx.y, tid = threadIdx.x;
    int wi = (wn >> 4) & 15, wj = wn & 15;
    size_t base = (size_t)wn * Tt * Cn + h * HDn;
    for (int idx = tid; idx < 640; idx += 256) {
        int key = idx >> 2, ch = idx & 3;
        s16x8 kv = {}, vv = {};
        if (key < Tt) {
            kv = *(const s16x8*)(K + base + (size_t)key * Cn + ch * 8);
            vv = *(const s16x8*)(V + base + (size_t)key * Cn + ch * 8);
        }
        *(s16x8*)(ldsK + (key >> 2) * 256 + (key & 3) * 64 + ch * 16) = kv;
        #pragma unroll
        for (int j = 0; j < 8; ++j)
            *(short*)(ldsV + (ch * 8 + j) * 336 + key * 2) = vv[j];
    }
    for (int idx = tid; idx < 2401; idx += 256) {
        int qp = idx / 49, kp = idx - qp * 49;
        int qpi = qp / 7, qpj = qp - qpi * 7, kpi = kp / 7, kpj = kp - kpi * 7;
        float bias = rpbf[h * 169 + (qpi - kpi + 6) * 13 + (qpj - kpj + 6)];
        int qi = wi * 7 + qpi, qj = wj * 7 + qpj, ki = wi * 7 + kpi, kj = wj * 7 + kpj;
        int rq = (qi < 105 ? 0 : (qi < 109 ? 1 : 2)) * 3 + (qj < 105 ? 0 : (qj < 109 ? 1 : 2));
        int rk = (ki < 105 ? 0 : (ki < 109 ? 1 : 2)) * 3 + (kj < 105 ? 0 : (kj < 109 ? 1 : 2));
        BM[qp * 52 + kp] = bias + (rq == rk ? 0.f : -100.f);
    }
    __syncthreads();
    int wv = tid >> 6, lane = tid & 63, l15 = lane & 15, lg = lane >> 4;
    char* myP = ldsP + wv * (16 * 336);
    for (int mt = wv; mt < 10; mt += 4) {
        int qrow = mt * 16 + l15; if (qrow > 146) qrow = 146;
        s16x8 qf = *(const s16x8*)(Q + base + (size_t)qrow * Cn + lg * 8);
        f32x4 acc[10];
        #pragma unroll
        for (int nt = 0; nt < 10; ++nt) {
            int key = nt * 16 + l15;
            s16x8 bfrag = *(const s16x8*)(ldsK + (key >> 2) * 256 + (key & 3) * 64 + lg * 16);
            f32x4 z = {};
            acc[nt] = MFMA(qf, bfrag, z);
        }
        float linv[4];
        #pragma unroll
        for (int r = 0; r < 4; ++r) {
            int row = mt * 16 + lg * 4 + r;
            int qp = row - (row >= 147 ? 147 : (row >= 98 ? 98 : (row >= 49 ? 49 : 0)));
            float s[10], m = -1e30f;
            #pragma unroll
            for (int nt = 0; nt < 10; ++nt) {
                int key = nt * 16 + l15;
                int kp = key - (key >= 147 ? 147 : (key >= 98 ? 98 : (key >= 49 ? 49 : 0)));
                float sv = acc[nt][r] + BM[qp * 52 + kp];
                if (nt == 9 && l15 >= 3) sv = -1e30f;
                s[nt] = sv;
                m = fmaxf(m, sv);
            }
            #pragma unroll
            for (int off = 1; off < 16; off <<= 1) m = fmaxf(m, __shfl_xor(m, off));
            float l = 0.f;
            #pragma unroll
            for (int nt = 0; nt < 10; ++nt) {
                float p = (nt == 9 && l15 >= 3) ? 0.f : __expf(s[nt] - m);
                l += p;
                *(bf16*)(myP + (lg * 4 + r) * 336 + (nt * 16 + l15) * 2) = f2bf(p);
            }
            #pragma unroll
            for (int off = 1; off < 16; off <<= 1) l += __shfl_xor(l, off);
            linv[r] = 1.f / l;
        }
        if (l15 == 0) {
            #pragma unroll
            for (int r = 0; r < 4; ++r) lArr[wv][lg * 4 + r] = linv[r];
        }
        float myinv = lArr[wv][l15];
        #pragma unroll
        for (int ntv = 0; ntv < 2; ++ntv) {
            f32x4 ao = {};
            #pragma unroll
            for (int ks = 0; ks < 5; ++ks) {
                s16x8 af = *(const s16x8*)(myP + l15 * 336 + ks * 64 + lg * 16);
                s16x8 vf = *(const s16x8*)(ldsV + (ntv * 16 + l15) * 336 + ks * 64 + lg * 16);
                ao = MFMA(vf, af, ao);   // swapped: D[dcol][q]
            }
            int q = mt * 16 + l15;
            if (q < Tt) {
                s16x4 pk;
                #pragma unroll
                for (int r = 0; r < 4; ++r) pk[r] = f2bs(ao[r] * myinv);
                *(s16x4*)(O + base + (size_t)q * Cn + ntv * 16 + lg * 4) = pk;
            }
        }
    }
}

// Output projection (swapped MFMA) + packed 8B residual RMW into xr
__global__ __launch_bounds__(256) void k_proj(
    const bf16* __restrict__ tokO, const float* __restrict__ P, const bf16* __restrict__ W,
    int bpOff, bf16* __restrict__ xr) {
    __shared__ char ldsA[160 * SA];
    __shared__ int rowIdx[Tt];
    int wn = blockIdx.x, tid = threadIdx.x;
    if (tid < Tt) rowIdx[tid] = tok_row(wn, tid);
    for (int i = tid; i < 13 * SA / 4; i += 256) ((int*)(ldsA + 147 * SA))[i] = 0;
    __syncthreads();
    for (int idx = tid; idx < Tt * 16; idx += 256) {
        int t = idx >> 4, c8 = idx & 15;
        s16x8 v = *(const s16x8*)(tokO + ((size_t)wn * Tt + t) * Cn + c8 * 8);
        *(s16x8*)(ldsA + t * SA + c8 * 16) = v;
    }
    __syncthreads();
    int wv = tid >> 6, lane = tid & 63, l15 = lane & 15, lg = lane >> 4;
    #pragma unroll 1
    for (int ni = 0; ni < 2; ++ni) {
        int nt = wv * 2 + ni;
        f32x4 acc[10] = {};
        #pragma unroll
        for (int ks = 0; ks < 4; ++ks) {
            s16x8 bfrag = *(const s16x8*)(W + (((nt << 2) + ks) * 64 + lane) * 8);
            #pragma unroll
            for (int mt = 0; mt < 10; ++mt) {
                s16x8 af = *(const s16x8*)(ldsA + (mt * 16 + l15) * SA + ks * 64 + lg * 16);
                acc[mt] = MFMA(bfrag, af, acc[mt]);
            }
        }
        int col0 = nt * 16 + lg * 4;
        f32x4 bp4 = *(const f32x4*)(P + bpOff + col0);
        #pragma unroll
        for (int mt = 0; mt < 10; ++mt) {
            int t = mt * 16 + l15;
            if (t < Tt) {
                size_t o = (size_t)rowIdx[t] * Cn + col0;
                s16x4 cur = *(const s16x4*)(xr + o);
                s16x4 pk;
                #pragma unroll
                for (int r = 0; r < 4; ++r) pk[r] = f2bs(bs2f(cur[r]) + acc[mt][r] + bp4[r]);
                *(s16x4*)(xr + o) = pk;
            }
        }
    }
}

// Fused LN3 + MLP: 48-token tile, parallel LN, prefetched B-frags, exp-GELU
__global__ __launch_bounds__(256) void k_mlp(
    const bf16* __restrict__ xr, const float* __restrict__ P, const bf16* __restrict__ wT,
    const int* __restrict__ dflag, void* __restrict__ outp) {
    __shared__ char ldsA[MT * SA];     // 13.5 KB
    __shared__ char ldsH[MT * SH];     // 49.5 KB
    __shared__ float gb[256];
    int tid = threadIdx.x;
    size_t t0 = (size_t)blockIdx.x * MT;
    gb[tid] = tid < 128 ? P[P_G3 + tid] : P[P_N3B + tid - 128];
    __syncthreads();
    for (int idx = tid; idx < MT * 16; idx += 256) {
        int t = idx >> 4, c8 = idx & 15;
        s16x8 v = *(const s16x8*)(xr + (t0 + t) * Cn + c8 * 8);
        *(s16x8*)(ldsA + t * SA + c8 * 16) = v;
    }
    __syncthreads();
    // parallel LN: 4 threads per row (waves 0-2 active, each fully)
    {
        int row = tid >> 2, sub = tid & 3;
        if (row < MT) {
            char* rp = ldsA + row * SA + sub * 64;
            float s = 0.f, s2 = 0.f;
            s16x8 vv[4];
            #pragma unroll
            for (int c = 0; c < 4; ++c) {
                vv[c] = *(const s16x8*)(rp + c * 16);
                #pragma unroll
                for (int j = 0; j < 8; ++j) { float fv = bs2f(vv[c][j]); s += fv; s2 += fv * fv; }
            }
            s  += __shfl_xor(s, 1);  s  += __shfl_xor(s, 2);
            s2 += __shfl_xor(s2, 1); s2 += __shfl_xor(s2, 2);
            float mean = s * (1.f / 128.f);
            float rstd = rsqrtf(s2 * (1.f / 128.f) - mean * mean + 1e-5f);
            #pragma unroll
            for (int c = 0; c < 4; ++c) {
                #pragma unroll
                for (int j = 0; j < 8; ++j) {
                    int col = sub * 32 + c * 8 + j;
                    vv[c][j] = f2bs((bs2f(vv[c][j]) - mean) * rstd * gb[col] + gb[128 + col]);
                }
                *(s16x8*)(rp + c * 16) = vv[c];
            }
        }
    }
    __syncthreads();
    int wv = tid >> 6, lane = tid & 63, l15 = lane & 15, lg = lane >> 4;
    const bf16* W1 = wT + W_W1T;
    {
        // token fragments (3 m-tiles x 4 ks) hoisted to registers
        s16x8 a[3][4];
        #pragma unroll
        for (int m = 0; m < 3; ++m)
            #pragma unroll
            for (int ks = 0; ks < 4; ++ks)
                a[m][ks] = *(const s16x8*)(ldsA + (m * 16 + l15) * SA + ks * 64 + lg * 16);
        int nt0 = wv * 8;
        s16x8 bc0 = *(const s16x8*)(W1 + (((nt0 << 2) + 0) * 64 + lane) * 8);
        s16x8 bc1 = *(const s16x8*)(W1 + (((nt0 << 2) + 1) * 64 + lane) * 8);
        s16x8 bc2 = *(const s16x8*)(W1 + (((nt0 << 2) + 2) * 64 + lane) * 8);
        s16x8 bc3 = *(const s16x8*)(W1 + (((nt0 << 2) + 3) * 64 + lane) * 8);
        #pragma unroll 1
        for (int ni = 0; ni < 8; ++ni) {
            int nt = nt0 + ni;
            // prefetch next n-tile's fragments (ni==7 reads into W2 region: harmless)
            s16x8 bn0 = *(const s16x8*)(W1 + ((((nt + 1) << 2) + 0) * 64 + lane) * 8);
            s16x8 bn1 = *(const s16x8*)(W1 + ((((nt + 1) << 2) + 1) * 64 + lane) * 8);
            s16x8 bn2 = *(const s16x8*)(W1 + ((((nt + 1) << 2) + 2) * 64 + lane) * 8);
            s16x8 bn3 = *(const s16x8*)(W1 + ((((nt + 1) << 2) + 3) * 64 + lane) * 8);
            f32x4 acc[3] = {};
            #pragma unroll
            for (int m = 0; m < 3; ++m) {
                acc[m] = MFMA(bc0, a[m][0], acc[m]);
                acc[m] = MFMA(bc1, a[m][1], acc[m]);
                acc[m] = MFMA(bc2, a[m][2], acc[m]);
                acc[m] = MFMA(bc3, a[m][3], acc[m]);
            }
            int col0 = nt * 16 + lg * 4;
            f32x4 b14 = *(const f32x4*)(P + P_B1 + col0);
            #pragma unroll
            for (int m = 0; m < 3; ++m) {
                s16x4 pk;
                #pragma unroll
                for (int r = 0; r < 4; ++r) pk[r] = f2bs(gelu(acc[m][r] + b14[r]));
                *(s16x4*)(ldsH + (m * 16 + l15) * SH + col0 * 2) = pk;
            }
            bc0 = bn0; bc1 = bn1; bc2 = bn2; bc3 = bn3;
        }
    }
    __syncthreads();
    const int f = *dflag;
    const bf16* W2 = wT + W_W2T;
    #pragma unroll 1
    for (int ni = 0; ni < 2; ++ni) {
        int nt = wv * 2 + ni;
        f32x4 acc[3] = {};
        s16x8 bc = *(const s16x8*)(W2 + (((nt << 4) + 0) * 64 + lane) * 8);
        #pragma unroll 1
        for (int ks = 0; ks < 16; ++ks) {
            s16x8 bn = *(const s16x8*)(W2 + (((nt << 4) + ks + 1) * 64 + lane) * 8);
            #pragma unroll
            for (int m = 0; m < 3; ++m) {
                s16x8 af = *(const s16x8*)(ldsH + (m * 16 + l15) * SH + ks * 64 + lg * 16);
                acc[m] = MFMA(bc, af, acc[m]);
            }
            bc = bn;
        }
        int col0 = nt * 16 + lg * 4;
        f32x4 b24 = *(const f32x4*)(P + P_B2 + col0);
        #pragma unroll
        for (int m = 0; m < 3; ++m) {
            size_t g = (t0 + m * 16 + l15) * Cn + col0;
            s16x4 cur = *(const s16x4*)(xr + g);
            if (f) {
                f32x4 o;
                #pragma unroll
                for (int r = 0; r < 4; ++r) o[r] = bs2f(cur[r]) + acc[m][r] + b24[r];
                *(f32x4*)((float*)outp + g) = o;
            } else {
                s16x4 pk;
                #pragma unroll
                for (int r = 0; r < 4; ++r) pk[r] = f2bs(bs2f(cur[r]) + acc[m][r] + b24[r]);
                *(s16x4*)((bf16*)outp + g) = pk;
            }
        }
    }
}

extern "C" void kernel_launch(void* const* d_in, const int* in_sizes, int n_in,
                              void* d_out, int out_size, void* d_ws, size_t ws_size,
                              hipStream_t stream) {
    Ptrs ptrs;
    for (int i = 0; i < 32; ++i) ptrs.p[i] = d_in[i];

    char* base = (char*)d_ws;
    float* P    = (float*)base;                   // 8192 f32 = 32 KB
    int*  dflag = (int*)(base + 32768);
    bf16* wT    = (bf16*)(base + 33024);          // 262144 bf16 = 512 KB
    bf16* xr    = wT + 262144;                    // NE bf16 residual
    bf16* tokK  = xr + NE;
    bf16* tokV  = tokK + NE;
    bf16* tokQ  = (bf16*)d_out;                   // Q and O alias in d_out

    k_detect<<<1, 256, 0, stream>>>((const unsigned int*)d_in[0], dflag);
    k_copy<<<(int)(NE / 2048), 256, 0, stream>>>(d_in[0], dflag, xr);
    k_params<<<1, 512, 0, stream>>>(ptrs, dflag, P);
    k_tsq<<<dim3(32, 8), 64, 0, stream>>>(ptrs, dflag, wT);
    k_tmlp<<<256, 64, 0, stream>>>(ptrs, dflag, wT);
    // ---- self-attention stage ----
    k_qkv_sa<<<WNt, 256, 0, stream>>>(xr, P, wT, tokQ, tokK, tokV);
    k_attn<<<dim3(WNt, HEADS), 256, 0, stream>>>(tokQ, tokK, tokV, tokQ, P + P_RPBSA);
    k_proj<<<WNt, 256, 0, stream>>>(tokQ, P, wT + W_SAP, P_BPSA, xr);
    // ---- cross-attention stage ----
    k_qkv_ca<<<WNt, 256, 0, stream>>>(xr, d_in[1], P, wT, dflag, tokQ, tokK, tokV);
    k_attn<<<dim3(WNt, HEADS), 256, 0, stream>>>(tokQ, tokK, tokV, tokQ, P + P_RPBCA);
    k_proj<<<WNt, 256, 0, stream>>>(tokQ, P, wT + W_CAP, P_BPCA, xr);
    // ---- MLP stage ----
    k_mlp<<<(int)(NE / Cn / MT), 256, 0, stream>>>(xr, P, wT, dflag, d_out);
}